// Round 16
// baseline (532.280 us; speedup 1.0000x reference)
//
#include <hip/hip_runtime.h>
#include <hip/hip_bf16.h>
#include <math.h>

#define D_MODEL 768
#define D_STATE 16
#define D_CONVW 4
#define D_INNER 1536
#define BATCH   2
#define SEQLEN  4096
#define NROWS   (BATCH*SEQLEN)       // 8192
#define NCHUNK  128                  // scan TLP: 1536 blocks for phases A/C
#define LCHUNK  (SEQLEN/NCHUNK)      // 32

typedef __attribute__((ext_vector_type(8))) short short8;
typedef __attribute__((ext_vector_type(4))) float floatx4;

__device__ inline unsigned short f2b(float x) {
    unsigned u = __float_as_uint(x);
    return (unsigned short)((u + 0x7fffu + ((u >> 16) & 1u)) >> 16);   // RNE
}
__device__ inline float b2f(unsigned short b) {
    return __uint_as_float(((unsigned)b) << 16);
}

#define GLDS(gp, lp) __builtin_amdgcn_global_load_lds( \
    (const __attribute__((address_space(1))) void*)(gp), \
    (__attribute__((address_space(3))) void*)(lp), 16, 0, 0)

// ---------------------------------------------------------------------------
// r16: 256x256 tile, BK=64, 8 waves — the m230-anchored "minimum 2-phase":
//   STEP(t): stage(t+1) -> compute(t) [64 MFMA/wave] -> vmcnt(0) -> barrier
// Lever = MFMA per barrier interval: 64 MFMA/wave per ONE barrier vs r15's
// 16 per TWO (m233: stage+vmcnt+barrier overhead ~800cy is the fixed cost;
// amortize it 8x).  2 buffers as 4 distinct __shared__ arrays (128 KiB,
// 1 block/CU — the template's own regime).  Granule XOR-swizzle for 128B
// rows: LDS slot = g ^ (row&7) (16-way -> 2-way = free), staged via
// inverse-swizzled global source (linear LDS dest, rule #21).
// Per-wave: 128x64 output = 8x4 frags; 24 ds_read_b128 + 64 MFMA / K-tile.
// EPI: 0 plain (OUTBF16 sel), 3 fused xp+delta (gn<32 -> f32 C2,
//      else softplus(acc+bias[gn-32]) -> bf16 Cv).  NT=K/64 must be even.
// Grid 1D = nbx*(M/256), %8==0.
// ---------------------------------------------------------------------------
template<int EPI, int OUTBF16>
__global__ __launch_bounds__(512, 2) void gemm_t256(
    const unsigned short* __restrict__ A, int lda,
    const unsigned short* __restrict__ Bt, int ldb,
    void* __restrict__ Cv, int ldc, float* __restrict__ C2,
    int N, int K, const float* __restrict__ bias, int nbx)
{
    __shared__ unsigned short As0[256*64], As1[256*64];
    __shared__ unsigned short Bs0[256*64], Bs1[256*64];

    // XCD-aware mapping (round-robin xcd; L2-friendly super-tiles when legal)
    const int nwg = gridDim.x;
    const int cpx = nwg >> 3;
    const int wg  = blockIdx.x;
    const int xcd = wg & 7, local = wg >> 3;
    int bmi, bni;
    if ((cpx % nbx == 0) && ((nbx & 1) == 0)) {
        const int R   = cpx / nbx;
        const int p   = local / (2 * R);
        const int idx = local % (2 * R);
        bmi = xcd * R + (idx >> 1);
        bni = p * 2 + (idx & 1);
    } else {
        const int swz = xcd * cpx + local;
        bmi = swz / nbx;
        bni = swz % nbx;
    }
    const int bm = bmi * 256;
    const int bn = bni * 256;

    const int tid  = threadIdx.x;          // 0..511
    const int lane = tid & 63;
    const int wave = tid >> 6;             // 0..7
    const int wr   = wave >> 2;            // 0..1 (M halves)
    const int wc   = wave & 3;             // 0..3 (N quarters)
    const int l15  = lane & 15;
    const int lg   = lane >> 4;

    // --- staging: 4 granules (16B) per thread per operand per K-tile ---
    // LDS linear dest: byte = q*8192 + tid*16  (row = q*64 + (tid>>3))
    // source granule col = (tid&7) ^ ((tid>>3)&7)  (inverse swizzle)
    const int srow = tid >> 3;                               // 0..63 (+q*64)
    const int sgc  = ((tid & 7) ^ ((tid >> 3) & 7)) * 8;     // shorts
    const unsigned short* pa = A  + (size_t)(bm + srow) * lda + sgc;
    const unsigned short* pb = Bt + (size_t)(bn + srow) * ldb + sgc;

    // --- LDS read byte offsets (kk=0; kk=1 is ^64) ---
    int aoff[8], boff[4];
    #pragma unroll
    for (int i = 0; i < 8; ++i) {
        const int row = wr * 128 + i * 16 + l15;
        aoff[i] = row * 128 + ((lg ^ (l15 & 7)) << 4);
    }
    #pragma unroll
    for (int j = 0; j < 4; ++j) {
        const int row = wc * 64 + j * 16 + l15;
        boff[j] = row * 128 + ((lg ^ (l15 & 7)) << 4);
    }

    floatx4 acc[8][4] = {};

    auto stage = [&](unsigned short (&SA)[256*64], unsigned short (&SB)[256*64]) {
        #pragma unroll
        for (int q = 0; q < 4; ++q)
            GLDS(pa + (size_t)q * 64 * lda, (char*)&SA[0] + q * 8192 + tid * 16);
        #pragma unroll
        for (int q = 0; q < 4; ++q)
            GLDS(pb + (size_t)q * 64 * ldb, (char*)&SB[0] + q * 8192 + tid * 16);
        pa += 64; pb += 64;
    };

    auto compute = [&](const unsigned short (&CA)[256*64],
                       const unsigned short (&CB)[256*64]) {
        #pragma unroll
        for (int kk = 0; kk < 2; ++kk) {
            const int kx = kk << 6;        // ^64 bytes selects k-half
            short8 af[8], bfv[4];
            #pragma unroll
            for (int i = 0; i < 8; ++i)
                af[i] = *(const short8*)((const char*)&CA[0] + (aoff[i] ^ kx));
            #pragma unroll
            for (int j = 0; j < 4; ++j)
                bfv[j] = *(const short8*)((const char*)&CB[0] + (boff[j] ^ kx));
            #pragma unroll
            for (int i = 0; i < 8; ++i)
                #pragma unroll
                for (int j = 0; j < 4; ++j)
                    acc[i][j] = __builtin_amdgcn_mfma_f32_16x16x32_bf16(
                        af[i], bfv[j], acc[i][j], 0, 0, 0);
        }
    };

    const int NT = K >> 6;                 // K/64, even for all uses (12, 24)

    stage(As0, Bs0);
    asm volatile("s_waitcnt vmcnt(0)" ::: "memory");
    __builtin_amdgcn_s_barrier();

    for (int t = 0; t < NT; t += 2) {
        if (t + 1 < NT) stage(As1, Bs1);
        compute(As0, Bs0);
        asm volatile("s_waitcnt vmcnt(0)" ::: "memory");
        __builtin_amdgcn_sched_barrier(0);
        __builtin_amdgcn_s_barrier();
        __builtin_amdgcn_sched_barrier(0);
        if (t + 2 < NT) stage(As0, Bs0);
        compute(As1, Bs1);
        asm volatile("s_waitcnt vmcnt(0)" ::: "memory");
        __builtin_amdgcn_sched_barrier(0);
        __builtin_amdgcn_s_barrier();
        __builtin_amdgcn_sched_barrier(0);
    }

    // C/D layout: col = lane&15, row = (lane>>4)*4 + reg  (m89-verified)
    #pragma unroll
    for (int i = 0; i < 8; ++i) {
        #pragma unroll
        for (int r = 0; r < 4; ++r) {
            const int gm = bm + wr * 128 + i * 16 + lg * 4 + r;
            #pragma unroll
            for (int j = 0; j < 4; ++j) {
                const int gn = bn + wc * 64 + j * 16 + l15;
                float v = acc[i][j][r];
                if (EPI == 3) {
                    if (gn < 32) {
                        C2[(size_t)gm * 32 + gn] = v;
                    } else if (gn < N) {
                        v += bias[gn - 32];
                        v = (v > 20.f) ? v : log1pf(__expf(v));
                        ((unsigned short*)Cv)[(size_t)gm * 1536 + gn - 32] = f2b(v);
                    }
                } else {
                    if (gn < N) {
                        if (OUTBF16)
                            ((unsigned short*)Cv)[(size_t)gm * ldc + gn] = f2b(v);
                        else
                            ((float*)Cv)[(size_t)gm * ldc + gn] = v;
                    }
                }
            }
        }
    }
}

// ---------------------------------------------------------------------------
// 128x128, 4 waves (r15) — small grids (Wcomb 144 blocks, out-proj 384).
// ---------------------------------------------------------------------------
template<int EPI, int OUTBF16>
__global__ __launch_bounds__(256, 4) void gemm_p2(
    const unsigned short* __restrict__ A, int lda,
    const unsigned short* __restrict__ Bt, int ldb,
    void* __restrict__ Cv, int ldc, float* __restrict__ C2,
    int N, int K, const float* __restrict__ bias, int nbx)
{
    __shared__ unsigned short As0[128*32], As1[128*32];
    __shared__ unsigned short Bs0[128*32], Bs1[128*32];

    const int nwg = gridDim.x;
    const int cpx = nwg >> 3;
    const int wg  = blockIdx.x;
    const int xcd = wg & 7, local = wg >> 3;
    int bmi, bni;
    if ((cpx % nbx == 0) && ((nbx & 1) == 0)) {
        const int R   = cpx / nbx;
        const int p   = local / (2 * R);
        const int idx = local % (2 * R);
        bmi = xcd * R + (idx >> 1);
        bni = p * 2 + (idx & 1);
    } else {
        const int swz = xcd * cpx + local;
        bmi = swz / nbx;
        bni = swz % nbx;
    }
    const int bm = bmi * 128;
    const int bn = bni * 128;

    const int tid  = threadIdx.x;
    const int lane = tid & 63;
    const int wave = tid >> 6;
    const int wm   = (wave >> 1) * 64;
    const int wn   = (wave & 1) * 64;
    const int l15  = lane & 15;
    const int lg   = lane >> 4;

    const int sr    = tid >> 2;
    const int sg    = ((tid & 3) ^ ((tid >> 3) & 3)) * 8;
    const int lbase = (tid & ~63) * 16;

    const unsigned short* pa0 = A  + (size_t)(bm + sr) * lda + sg;
    const unsigned short* pa1 = A  + (size_t)(bm + 64 + sr) * lda + sg;
    const unsigned short* pb0 = Bt + (size_t)(bn + sr) * ldb + sg;
    const unsigned short* pb1 = Bt + (size_t)(bn + 64 + sr) * ldb + sg;

    int aoff[4], boff[4];
    #pragma unroll
    for (int i = 0; i < 4; ++i) {
        const int tr = wm + i * 16 + l15;
        aoff[i] = tr * 64 + ((lg ^ ((tr >> 1) & 3)) << 4);
    }
    #pragma unroll
    for (int j = 0; j < 4; ++j) {
        const int tr = wn + j * 16 + l15;
        boff[j] = tr * 64 + ((lg ^ ((tr >> 1) & 3)) << 4);
    }

    floatx4 acc[4][4] = {};

    auto stage = [&](unsigned short (&SA)[128*32], unsigned short (&SB)[128*32]) {
        GLDS(pa0, (char*)SA + lbase);
        GLDS(pa1, (char*)SA + 4096 + lbase);
        GLDS(pb0, (char*)SB + lbase);
        GLDS(pb1, (char*)SB + 4096 + lbase);
        pa0 += 32; pa1 += 32; pb0 += 32; pb1 += 32;
    };

    auto compute = [&](const unsigned short (&CA)[128*32],
                       const unsigned short (&CB)[128*32]) {
        short8 af[4], bfv[4];
        #pragma unroll
        for (int i = 0; i < 4; ++i)
            af[i] = *(const short8*)((const char*)&CA[0] + aoff[i]);
        #pragma unroll
        for (int j = 0; j < 4; ++j)
            bfv[j] = *(const short8*)((const char*)&CB[0] + boff[j]);
        #pragma unroll
        for (int i = 0; i < 4; ++i)
            #pragma unroll
            for (int j = 0; j < 4; ++j)
                acc[i][j] = __builtin_amdgcn_mfma_f32_16x16x32_bf16(
                    af[i], bfv[j], acc[i][j], 0, 0, 0);
    };

    const int NT = K >> 5;                 // K/32, even

    stage(As0, Bs0);

    #define STEP(SA, SB, CA, CB, T)                                          \
    {                                                                        \
        if ((T) + 1 < NT) {                                                  \
            stage(SA, SB);                                                   \
            asm volatile("s_waitcnt vmcnt(4)" ::: "memory");                 \
        } else {                                                             \
            asm volatile("s_waitcnt vmcnt(0)" ::: "memory");                 \
        }                                                                    \
        __builtin_amdgcn_sched_barrier(0);                                   \
        __builtin_amdgcn_s_barrier();                                        \
        __builtin_amdgcn_sched_barrier(0);                                   \
        compute(CA, CB);                                                     \
        __builtin_amdgcn_sched_barrier(0);                                   \
        __builtin_amdgcn_s_barrier();                                        \
        __builtin_amdgcn_sched_barrier(0);                                   \
    }

    for (int t = 0; t < NT; t += 2) {
        STEP(As1, Bs1, As0, Bs0, t);
        STEP(As0, Bs0, As1, Bs1, t + 1);
    }
    #undef STEP

    #pragma unroll
    for (int i = 0; i < 4; ++i) {
        #pragma unroll
        for (int r = 0; r < 4; ++r) {
            const int gm = bm + wm + i * 16 + lg * 4 + r;
            #pragma unroll
            for (int j = 0; j < 4; ++j) {
                const int gn = bn + wn + j * 16 + l15;
                float v = acc[i][j][r];
                if (gn < N) {
                    if (OUTBF16)
                        ((unsigned short*)Cv)[(size_t)gm * ldc + gn] = f2b(v);
                    else
                        ((float*)Cv)[(size_t)gm * ldc + gn] = v;
                }
            }
        }
    }
}

// ---------------------------------------------------------------------------
// W[K][N] f32 -> Wt[N_pad][K] bf16 (pad rows zeroed).  32x32 LDS transpose.
// ---------------------------------------------------------------------------
__global__ __launch_bounds__(256) void transpose_bf16(
    const float* __restrict__ W, unsigned short* __restrict__ Wt, int K, int N)
{
    __shared__ float t[32][33];
    const int nt = blockIdx.x * 32, kt = blockIdx.y * 32;
    const int tx = threadIdx.x & 31, ty = threadIdx.x >> 5;
    #pragma unroll
    for (int r = 0; r < 4; ++r) {
        const int k = ty + r * 8;
        const int n = nt + tx;
        float v = 0.f;
        if (n < N) v = W[(size_t)(kt + k) * N + n];
        t[k][tx] = v;
    }
    __syncthreads();
    #pragma unroll
    for (int r = 0; r < 4; ++r) {
        const int nl = ty + r * 8;
        Wt[(size_t)(nt + nl) * K + kt + tx] = f2b(t[tx][nl]);
    }
}

__global__ __launch_bounds__(256) void f32_to_bf16(
    const float* __restrict__ in, unsigned short* __restrict__ o, int n4)
{
    const int i = blockIdx.x * 256 + threadIdx.x;
    if (i >= n4) return;
    float4 v = ((const float4*)in)[i];
    ushort4 r;
    r.x = f2b(v.x); r.y = f2b(v.y); r.z = f2b(v.z); r.w = f2b(v.w);
    ((ushort4*)o)[i] = r;
}

// W_x[:, 32:] f32 (stride 1568) -> wxb[1536][1536] bf16
__global__ __launch_bounds__(256) void wx32_to_bf16(
    const float* __restrict__ Wx, unsigned short* __restrict__ o)
{
    const int i = blockIdx.x * 256 + threadIdx.x;   // over 1536*384
    if (i >= 1536 * 384) return;
    const int row = i / 384, q = i % 384;
    float4 v = *(const float4*)(Wx + (size_t)row * 1568 + 32 + q * 4);
    ushort4 r;
    r.x = f2b(v.x); r.y = f2b(v.y); r.z = f2b(v.z); r.w = f2b(v.w);
    *(ushort4*)(o + (size_t)row * 1536 + q * 4) = r;
}

// ---------------------------------------------------------------------------
// Depthwise causal conv (width 4) + bias + SiLU, 8 channels/thread, bf16.
// ---------------------------------------------------------------------------
__global__ __launch_bounds__(256) void conv_silu8(
    const unsigned short* __restrict__ xzb, const float* __restrict__ w,
    const float* __restrict__ cb, unsigned short* __restrict__ ub)
{
    const int i = blockIdx.x * 256 + threadIdx.x;    // over NROWS*192
    if (i >= NROWS * 192) return;
    const int g   = i % 192;
    const int row = i / 192;
    const int l   = row % SEQLEN;
    const int d0  = g * 8;

    short8 xr[4];
    #pragma unroll
    for (int k = 0; k < 4; ++k) {
        const int ll = l - 3 + k;
        if (ll >= 0)
            xr[k] = *(const short8*)&xzb[(size_t)(row - 3 + k) * 3072 + d0];
        else
            xr[k] = short8{0,0,0,0,0,0,0,0};
    }
    unsigned short o[8];
    #pragma unroll
    for (int e = 0; e < 8; ++e) {
        float4 we = *(const float4*)&w[(d0 + e) * 4];
        float a = cb[d0 + e];
        a = fmaf(b2f((unsigned short)xr[0][e]), we.x, a);
        a = fmaf(b2f((unsigned short)xr[1][e]), we.y, a);
        a = fmaf(b2f((unsigned short)xr[2][e]), we.z, a);
        a = fmaf(b2f((unsigned short)xr[3][e]), we.w, a);
        o[e] = f2b(a / (1.f + __expf(-a)));
    }
    *(short8*)&ub[(size_t)row * 1536 + d0] = *(short8*)o;
}

// ---------------------------------------------------------------------------
// Per-row softmax over B (16) + copy C (16) from compact xp32[row][32].
// ---------------------------------------------------------------------------
__global__ __launch_bounds__(256) void softmax_bc_kernel(
    const float* __restrict__ xp32, float* __restrict__ Bsm, float* __restrict__ Csm)
{
    const int row = blockIdx.x * 256 + threadIdx.x;
    if (row >= NROWS) return;
    const float* p = xp32 + (size_t)row * 32;
    float v[16];
    #pragma unroll
    for (int q = 0; q < 4; ++q) {
        float4 t = *(const float4*)(p + q * 4);
        v[q*4+0]=t.x; v[q*4+1]=t.y; v[q*4+2]=t.z; v[q*4+3]=t.w;
    }
    float mx = v[0];
    #pragma unroll
    for (int s = 1; s < 16; ++s) mx = fmaxf(mx, v[s]);
    float sum = 0.f;
    #pragma unroll
    for (int s = 0; s < 16; ++s) { v[s] = __expf(v[s] - mx); sum += v[s]; }
    const float inv = 1.f / sum;
    float* bo = Bsm + (size_t)row * 16;
    float* co = Csm + (size_t)row * 16;
    #pragma unroll
    for (int s = 0; s < 16; ++s) bo[s] = v[s] * inv;
    #pragma unroll
    for (int q = 0; q < 4; ++q)
        *(float4*)(co + q * 4) = *(const float4*)(p + 16 + q * 4);
}

// ---------------------------------------------------------------------------
// Scan phase A: per (b, chunk, d): chunk-final state (zero init) + dt-sum.
// ---------------------------------------------------------------------------
__global__ __launch_bounds__(256) void scan_chunk_state(
    const unsigned short* __restrict__ deltab, const unsigned short* __restrict__ ub,
    const float* __restrict__ Bsm, const float* __restrict__ A_log,
    float* __restrict__ chunkS, float* __restrict__ dtsum)
{
    const int gid = blockIdx.x * 256 + threadIdx.x;   // (b*NCHUNK+c)*D_INNER+d
    const int d = gid % D_INNER;
    const int c = (gid / D_INNER) % NCHUNK;
    const int b = gid / (D_INNER * NCHUNK);

    float A2[16];
    #pragma unroll
    for (int q = 0; q < 4; ++q) {
        float4 t = *(const float4*)(A_log + d * 16 + q * 4);
        A2[q*4+0] = -__expf(t.x) * 1.44269504089f;
        A2[q*4+1] = -__expf(t.y) * 1.44269504089f;
        A2[q*4+2] = -__expf(t.z) * 1.44269504089f;
        A2[q*4+3] = -__expf(t.w) * 1.44269504089f;
    }
    float h[16];
    #pragma unroll
    for (int s = 0; s < 16; ++s) h[s] = 0.f;
    float dts = 0.f;

    const int t0 = c * LCHUNK;
    for (int t = t0; t < t0 + LCHUNK; ++t) {
        const size_t rowoff = (size_t)b * SEQLEN + t;
        const float dt = b2f(deltab[rowoff * D_INNER + d]);
        const float uu = b2f(ub[rowoff * D_INNER + d]);
        const float du = dt * uu;
        dts += dt;
        const float4* Bp = (const float4*)(Bsm + rowoff * 16);
        float Bv[16];
        #pragma unroll
        for (int q = 0; q < 4; ++q) {
            float4 tb = Bp[q];
            Bv[q*4+0]=tb.x; Bv[q*4+1]=tb.y; Bv[q*4+2]=tb.z; Bv[q*4+3]=tb.w;
        }
        #pragma unroll
        for (int s = 0; s < 16; ++s) {
            const float dA = exp2f(dt * A2[s]);
            h[s] = fmaf(dA, h[s], du * Bv[s]);
        }
    }
    float* S = chunkS + (size_t)gid * 16;
    #pragma unroll
    for (int q = 0; q < 4; ++q)
        *(float4*)(S + q * 4) = make_float4(h[q*4+0], h[q*4+1], h[q*4+2], h[q*4+3]);
    dtsum[gid] = dts;
}

// ---------------------------------------------------------------------------
// Scan phase B: inter-chunk scan; chunkS becomes chunk-INITIAL states.
// ---------------------------------------------------------------------------
__global__ __launch_bounds__(256) void scan_chunk_scan(
    const float* __restrict__ A_log, const float* __restrict__ dtsum,
    float* __restrict__ chunkS)
{
    const int gid = blockIdx.x * 256 + threadIdx.x;   // (b*D_INNER+d)*16+s
    if (gid >= BATCH * D_INNER * 16) return;
    const int s = gid % 16;
    const int d = (gid / 16) % D_INNER;
    const int b = gid / (16 * D_INNER);
    const float A2 = -__expf(A_log[d * 16 + s]) * 1.44269504089f;
    float hprev = 0.f;
    for (int c = 0; c < NCHUNK; ++c) {
        const size_t cidx = ((size_t)(b * NCHUNK + c) * D_INNER + d);
        const float P  = exp2f(A2 * dtsum[cidx]);
        const size_t idx = cidx * 16 + s;
        const float Sc = chunkS[idx];
        chunkS[idx] = hprev;
        hprev = fmaf(P, hprev, Sc);
    }
}

// ---------------------------------------------------------------------------
// Scan phase C: re-run chunks from initial states, y = (C.h) * silu(z), bf16.
// ---------------------------------------------------------------------------
__global__ __launch_bounds__(256) void scan_output(
    const unsigned short* __restrict__ deltab, const unsigned short* __restrict__ ub,
    const float* __restrict__ Bsm, const float* __restrict__ Csm,
    const float* __restrict__ A_log, const float* __restrict__ chunkS,
    const unsigned short* __restrict__ xzb, unsigned short* __restrict__ yb)
{
    const int gid = blockIdx.x * 256 + threadIdx.x;
    const int d = gid % D_INNER;
    const int c = (gid / D_INNER) % NCHUNK;
    const int b = gid / (D_INNER * NCHUNK);

    float A2[16];
    #pragma unroll
    for (int q = 0; q < 4; ++q) {
        float4 t = *(const float4*)(A_log + d * 16 + q * 4);
        A2[q*4+0] = -__expf(t.x) * 1.44269504089f;
        A2[q*4+1] = -__expf(t.y) * 1.44269504089f;
        A2[q*4+2] = -__expf(t.z) * 1.44269504089f;
        A2[q*4+3] = -__expf(t.w) * 1.44269504089f;
    }
    float h[16];
    const float* S = chunkS + (size_t)gid * 16;
    #pragma unroll
    for (int q = 0; q < 4; ++q) {
        float4 t = *(const float4*)(S + q * 4);
        h[q*4+0]=t.x; h[q*4+1]=t.y; h[q*4+2]=t.z; h[q*4+3]=t.w;
    }

    const int t0 = c * LCHUNK;
    for (int t = t0; t < t0 + LCHUNK; ++t) {
        const size_t rowoff = (size_t)b * SEQLEN + t;
        const float dt = b2f(deltab[rowoff * D_INNER + d]);
        const float uu = b2f(ub[rowoff * D_INNER + d]);
        const float du = dt * uu;
        const float4* Bp = (const float4*)(Bsm + rowoff * 16);
        const float4* Cp = (const float4*)(Csm + rowoff * 16);
        float Bv[16], Cv[16];
        #pragma unroll
        for (int q = 0; q < 4; ++q) {
            float4 tb = Bp[q], tc = Cp[q];
            Bv[q*4+0]=tb.x; Bv[q*4+1]=tb.y; Bv[q*4+2]=tb.z; Bv[q*4+3]=tb.w;
            Cv[q*4+0]=tc.x; Cv[q*4+1]=tc.y; Cv[q*4+2]=tc.z; Cv[q*4+3]=tc.w;
        }
        float yv = 0.f;
        #pragma unroll
        for (int s = 0; s < 16; ++s) {
            const float dA = exp2f(dt * A2[s]);
            h[s] = fmaf(dA, h[s], du * Bv[s]);
            yv = fmaf(Cv[s], h[s], yv);
        }
        const float z = b2f(xzb[rowoff * (2 * D_INNER) + D_INNER + d]);
        const float sz = z / (1.f + __expf(-z));
        yb[rowoff * D_INNER + d] = f2b(yv * sz);
    }
}

// ---------------------------------------------------------------------------
extern "C" void kernel_launch(void* const* d_in, const int* in_sizes, int n_in,
                              void* d_out, int out_size, void* d_ws, size_t ws_size,
                              hipStream_t stream)
{
    const float* hs     = (const float*)d_in[0];
    const float* W_in   = (const float*)d_in[1];
    const float* conv_w = (const float*)d_in[2];
    const float* conv_b = (const float*)d_in[3];
    const float* W_x    = (const float*)d_in[4];
    const float* W_dt   = (const float*)d_in[5];
    const float* b_dt   = (const float*)d_in[6];
    const float* A_log  = (const float*)d_in[7];
    const float* W_out  = (const float*)d_in[9];
    float* out = (float*)d_out;

    // workspace layout (256B aligned)
    char* w = (char*)d_ws;
    auto alloc = [&](size_t bytes) { char* p = w; w += (bytes + 255) & ~(size_t)255; return p; };
    float*          xp32   = (float*)alloc((size_t)NROWS * 32 * 4);
    unsigned short* deltab = (unsigned short*)alloc((size_t)NROWS * 1536 * 2);
    float*          Bsm    = (float*)alloc((size_t)NROWS * 16 * 4);
    float*          Csm    = (float*)alloc((size_t)NROWS * 16 * 4);
    float*          chunkS = (float*)alloc((size_t)BATCH * NCHUNK * D_INNER * 16 * 4);
    float*          dtsum  = (float*)alloc((size_t)BATCH * NCHUNK * D_INNER * 4);
    unsigned short* xzb    = (unsigned short*)alloc((size_t)NROWS * 3072 * 2);
    unsigned short* ub     = (unsigned short*)alloc((size_t)NROWS * 1536 * 2);
    unsigned short* yb     = (unsigned short*)alloc((size_t)NROWS * 1536 * 2);
    unsigned short* hsb    = (unsigned short*)alloc((size_t)NROWS * 768 * 2);
    unsigned short* Wt_in  = (unsigned short*)alloc((size_t)3072 * 768 * 2);
    unsigned short* Wt_x   = (unsigned short*)alloc((size_t)1792 * 1536 * 2);
    unsigned short* Wt_dt  = (unsigned short*)alloc((size_t)1536 * 1536 * 2);
    unsigned short* Wt_out = (unsigned short*)alloc((size_t)768 * 1536 * 2);
    unsigned short* wxb    = (unsigned short*)alloc((size_t)1536 * 1536 * 2);

    const dim3 blk(256);

    // 0) weight transposes + converts
    transpose_bf16<<<dim3(3072/32, 768/32),  blk, 0, stream>>>(W_in,  Wt_in,  768,  3072);
    transpose_bf16<<<dim3(1792/32, 1536/32), blk, 0, stream>>>(W_x,   Wt_x,   1536, 1568);
    transpose_bf16<<<dim3(1536/32, 1536/32), blk, 0, stream>>>(W_dt,  Wt_dt,  1536, 1536);
    transpose_bf16<<<dim3(768/32,  1536/32), blk, 0, stream>>>(W_out, Wt_out, 1536, 768);
    f32_to_bf16<<<(NROWS*768/4 + 255)/256, blk, 0, stream>>>(hs, hsb, NROWS*768/4);
    wx32_to_bf16<<<(1536*384 + 255)/256, blk, 0, stream>>>(W_x, wxb);

    // 0b) W_comb^T = (W_x[:,32:] @ W_dt)^T spliced into Wt_x rows 32..1567:
    //     [M=1536, N=1536, K=1536; grid 144; 128^2 kernel]
    gemm_p2<0,1><<<dim3(144), blk, 0, stream>>>(
        Wt_dt, 1536, wxb, 1536, Wt_x + (size_t)32 * 1536, 1536, nullptr,
        1536, 1536, nullptr, 12);

    // 1) xz = hs @ W_in  (bf16 out)  [256^2 2-phase; K=768, NT=12; grid 32*12=384]
    gemm_t256<0,1><<<dim3(384), dim3(512), 0, stream>>>(
        hsb, 768, Wt_in, 768, xzb, 3072, nullptr, 3072, 768, nullptr, 12);

    // 2) u = silu(conv(x) + cb)
    conv_silu8<<<(NROWS*192)/256, blk, 0, stream>>>(xzb, conv_w, conv_b, ub);

    // 3) fused xp+delta GEMM: u @ [W_x[:,:32] | W_comb]
    //    [256^2 2-phase; K=1536, NT=24; grid 32*7=224, %8==0]
    gemm_t256<3,0><<<dim3(224), dim3(512), 0, stream>>>(
        ub, 1536, Wt_x, 1536, deltab, 1536, xp32, 1568, 1536, b_dt, 7);

    // 4) Bsm = softmax(xp32[:, :16]), Csm = xp32[:, 16:32]
    softmax_bc_kernel<<<NROWS/256, blk, 0, stream>>>(xp32, Bsm, Csm);

    // 5-7) chunked selective scan (NCHUNK=128: 1536 blocks for A/C)
    scan_chunk_state<<<(BATCH*NCHUNK*D_INNER)/256, blk, 0, stream>>>(
        deltab, ub, Bsm, A_log, chunkS, dtsum);
    scan_chunk_scan<<<(BATCH*D_INNER*16 + 255)/256, blk, 0, stream>>>(
        A_log, dtsum, chunkS);
    scan_output<<<(BATCH*NCHUNK*D_INNER)/256, blk, 0, stream>>>(
        deltab, ub, Bsm, Csm, A_log, chunkS, xzb, yb);

    // 8) out = y @ W_out  (f32 out)  [128^2; grid 6*64=384, %8==0]
    gemm_p2<0,0><<<dim3(384), blk, 0, stream>>>(
        yb, 1536, Wt_out, 1536, out, 768, nullptr, 768, 1536, nullptr, 6);
}

// Round 17
// 445.949 us; speedup vs baseline: 1.1936x; 1.1936x over previous
//
#include <hip/hip_runtime.h>
#include <hip/hip_bf16.h>
#include <math.h>

#define D_MODEL 768
#define D_STATE 16
#define D_CONVW 4
#define D_INNER 1536
#define BATCH   2
#define SEQLEN  4096
#define NROWS   (BATCH*SEQLEN)       // 8192
#define NCHUNK  128                  // scan TLP: 1536 blocks for phases A/C
#define LCHUNK  (SEQLEN/NCHUNK)      // 32

typedef __attribute__((ext_vector_type(8))) short short8;
typedef __attribute__((ext_vector_type(4))) float floatx4;

__device__ inline unsigned short f2b(float x) {
    unsigned u = __float_as_uint(x);
    return (unsigned short)((u + 0x7fffu + ((u >> 16) & 1u)) >> 16);   // RNE
}
__device__ inline float b2f(unsigned short b) {
    return __uint_as_float(((unsigned)b) << 16);
}

#define GLDS(gp, lp) __builtin_amdgcn_global_load_lds( \
    (const __attribute__((address_space(1))) void*)(gp), \
    (__attribute__((address_space(3))) void*)(lp), 16, 0, 0)

// ---------------------------------------------------------------------------
// r17 = r15 revert (best measured family, 442.6us) + 64x64 small-tile GEMM
// for the grid-starved Wcomb (144 blocks = 0.56/CU was half-idle).
// GEMM structure ceiling note (r4..r16): >=48KB-LDS/1-2 blocks/CU configs
// all land 170-280us; ~3+ blocks/CU configs land 113-117us.  Inter-block
// TLP is the operative latency-hiding mechanism here; keep small LDS and
// multi-block residency.
// ---------------------------------------------------------------------------

// 256x128 (MxN), 8 waves.  Grid 1D = nbx*(M/256), %8==0.  NT=K/32 even.
// EPI: 0 plain (OUTBF16 sel), 3 fused xp+delta (gn<32 -> f32 C2,
//      else softplus(acc+bias[gn-32]) -> bf16 Cv).
template<int EPI, int OUTBF16>
__global__ __launch_bounds__(512, 4) void gemm_w8(
    const unsigned short* __restrict__ A, int lda,
    const unsigned short* __restrict__ Bt, int ldb,
    void* __restrict__ Cv, int ldc, float* __restrict__ C2,
    int N, int K, const float* __restrict__ bias, int nbx)
{
    __shared__ unsigned short As0[256*32], As1[256*32];
    __shared__ unsigned short Bs0[128*32], Bs1[128*32];

    const int nwg = gridDim.x;
    const int cpx = nwg >> 3;
    const int wg  = blockIdx.x;
    const int xcd = wg & 7, local = wg >> 3;
    int bmi, bni;
    if ((cpx % nbx == 0) && ((nbx & 1) == 0)) {
        const int R   = cpx / nbx;
        const int p   = local / (2 * R);
        const int idx = local % (2 * R);
        bmi = xcd * R + (idx >> 1);
        bni = p * 2 + (idx & 1);
    } else {
        const int swz = xcd * cpx + local;
        bmi = swz / nbx;
        bni = swz % nbx;
    }
    const int bm = bmi * 256;
    const int bn = bni * 128;

    const int tid  = threadIdx.x;          // 0..511
    const int lane = tid & 63;
    const int wave = tid >> 6;             // 0..7
    const int wm   = (wave >> 1) * 64;     // 0,64,128,192
    const int wn   = (wave & 1) * 64;      // 0,64
    const int l15  = lane & 15;
    const int lg   = lane >> 4;

    const int sr    = tid >> 2;                              // 0..127
    const int sg    = ((tid & 3) ^ ((tid >> 3) & 3)) * 8;    // swizzled src granule
    const int lbase = (tid & ~63) * 16;                      // wave-uniform LDS base

    const unsigned short* pa0 = A  + (size_t)(bm + sr) * lda + sg;
    const unsigned short* pa1 = A  + (size_t)(bm + 128 + sr) * lda + sg;
    const unsigned short* pb0 = Bt + (size_t)(bn + sr) * ldb + sg;

    int aoff[4], boff[4];
    #pragma unroll
    for (int i = 0; i < 4; ++i) {
        const int tr = wm + i * 16 + l15;
        aoff[i] = tr * 64 + ((lg ^ ((tr >> 1) & 3)) << 4);
    }
    #pragma unroll
    for (int j = 0; j < 4; ++j) {
        const int tr = wn + j * 16 + l15;
        boff[j] = tr * 64 + ((lg ^ ((tr >> 1) & 3)) << 4);
    }

    floatx4 acc[4][4] = {};

    auto stage = [&](unsigned short (&SA)[256*32], unsigned short (&SB)[128*32]) {
        GLDS(pa0, (char*)SA + lbase);
        GLDS(pa1, (char*)SA + 8192 + lbase);
        GLDS(pb0, (char*)SB + lbase);
        pa0 += 32; pa1 += 32; pb0 += 32;
    };

    auto compute = [&](const unsigned short (&CA)[256*32],
                       const unsigned short (&CB)[128*32]) {
        short8 af[4], bfv[4];
        #pragma unroll
        for (int i = 0; i < 4; ++i)
            af[i] = *(const short8*)((const char*)&CA[0] + aoff[i]);
        #pragma unroll
        for (int j = 0; j < 4; ++j)
            bfv[j] = *(const short8*)((const char*)&CB[0] + boff[j]);
        #pragma unroll
        for (int i = 0; i < 4; ++i)
            #pragma unroll
            for (int j = 0; j < 4; ++j)
                acc[i][j] = __builtin_amdgcn_mfma_f32_16x16x32_bf16(
                    af[i], bfv[j], acc[i][j], 0, 0, 0);
    };

    const int NT = K >> 5;                 // K/32, even

    stage(As0, Bs0);                       // prologue: tile 0 -> buf0

    #define STEP(SA, SB, CA, CB, T)                                          \
    {                                                                        \
        if ((T) + 1 < NT) {                                                  \
            stage(SA, SB);                                                   \
            asm volatile("s_waitcnt vmcnt(3)" ::: "memory");                 \
        } else {                                                             \
            asm volatile("s_waitcnt vmcnt(0)" ::: "memory");                 \
        }                                                                    \
        __builtin_amdgcn_sched_barrier(0);                                   \
        __builtin_amdgcn_s_barrier();                                        \
        __builtin_amdgcn_sched_barrier(0);                                   \
        compute(CA, CB);                                                     \
        __builtin_amdgcn_sched_barrier(0);                                   \
        __builtin_amdgcn_s_barrier();                                        \
        __builtin_amdgcn_sched_barrier(0);                                   \
    }

    for (int t = 0; t < NT; t += 2) {
        STEP(As1, Bs1, As0, Bs0, t);
        STEP(As0, Bs0, As1, Bs1, t + 1);
    }
    #undef STEP

    // C/D layout: col = lane&15, row = (lane>>4)*4 + reg  (m89-verified)
    #pragma unroll
    for (int i = 0; i < 4; ++i) {
        #pragma unroll
        for (int r = 0; r < 4; ++r) {
            const int gm = bm + wm + i * 16 + lg * 4 + r;
            #pragma unroll
            for (int j = 0; j < 4; ++j) {
                const int gn = bn + wn + j * 16 + l15;
                float v = acc[i][j][r];
                if (EPI == 3) {
                    if (gn < 32) {
                        C2[(size_t)gm * 32 + gn] = v;
                    } else if (gn < N) {
                        v += bias[gn - 32];
                        v = (v > 20.f) ? v : log1pf(__expf(v));
                        ((unsigned short*)Cv)[(size_t)gm * 1536 + gn - 32] = f2b(v);
                    }
                } else {
                    if (gn < N) {
                        if (OUTBF16)
                            ((unsigned short*)Cv)[(size_t)gm * ldc + gn] = f2b(v);
                        else
                            ((float*)Cv)[(size_t)gm * ldc + gn] = v;
                    }
                }
            }
        }
    }
}

// 128x128, 4 waves — out-proj (384 blocks).
template<int EPI, int OUTBF16>
__global__ __launch_bounds__(256, 4) void gemm_p2(
    const unsigned short* __restrict__ A, int lda,
    const unsigned short* __restrict__ Bt, int ldb,
    void* __restrict__ Cv, int ldc, float* __restrict__ C2,
    int N, int K, const float* __restrict__ bias, int nbx)
{
    __shared__ unsigned short As0[128*32], As1[128*32];
    __shared__ unsigned short Bs0[128*32], Bs1[128*32];

    const int nwg = gridDim.x;
    const int cpx = nwg >> 3;
    const int wg  = blockIdx.x;
    const int xcd = wg & 7, local = wg >> 3;
    int bmi, bni;
    if ((cpx % nbx == 0) && ((nbx & 1) == 0)) {
        const int R   = cpx / nbx;
        const int p   = local / (2 * R);
        const int idx = local % (2 * R);
        bmi = xcd * R + (idx >> 1);
        bni = p * 2 + (idx & 1);
    } else {
        const int swz = xcd * cpx + local;
        bmi = swz / nbx;
        bni = swz % nbx;
    }
    const int bm = bmi * 128;
    const int bn = bni * 128;

    const int tid  = threadIdx.x;
    const int lane = tid & 63;
    const int wave = tid >> 6;
    const int wm   = (wave >> 1) * 64;
    const int wn   = (wave & 1) * 64;
    const int l15  = lane & 15;
    const int lg   = lane >> 4;

    const int sr    = tid >> 2;
    const int sg    = ((tid & 3) ^ ((tid >> 3) & 3)) * 8;
    const int lbase = (tid & ~63) * 16;

    const unsigned short* pa0 = A  + (size_t)(bm + sr) * lda + sg;
    const unsigned short* pa1 = A  + (size_t)(bm + 64 + sr) * lda + sg;
    const unsigned short* pb0 = Bt + (size_t)(bn + sr) * ldb + sg;
    const unsigned short* pb1 = Bt + (size_t)(bn + 64 + sr) * ldb + sg;

    int aoff[4], boff[4];
    #pragma unroll
    for (int i = 0; i < 4; ++i) {
        const int tr = wm + i * 16 + l15;
        aoff[i] = tr * 64 + ((lg ^ ((tr >> 1) & 3)) << 4);
    }
    #pragma unroll
    for (int j = 0; j < 4; ++j) {
        const int tr = wn + j * 16 + l15;
        boff[j] = tr * 64 + ((lg ^ ((tr >> 1) & 3)) << 4);
    }

    floatx4 acc[4][4] = {};

    auto stage = [&](unsigned short (&SA)[128*32], unsigned short (&SB)[128*32]) {
        GLDS(pa0, (char*)SA + lbase);
        GLDS(pa1, (char*)SA + 4096 + lbase);
        GLDS(pb0, (char*)SB + lbase);
        GLDS(pb1, (char*)SB + 4096 + lbase);
        pa0 += 32; pa1 += 32; pb0 += 32; pb1 += 32;
    };

    auto compute = [&](const unsigned short (&CA)[128*32],
                       const unsigned short (&CB)[128*32]) {
        short8 af[4], bfv[4];
        #pragma unroll
        for (int i = 0; i < 4; ++i)
            af[i] = *(const short8*)((const char*)&CA[0] + aoff[i]);
        #pragma unroll
        for (int j = 0; j < 4; ++j)
            bfv[j] = *(const short8*)((const char*)&CB[0] + boff[j]);
        #pragma unroll
        for (int i = 0; i < 4; ++i)
            #pragma unroll
            for (int j = 0; j < 4; ++j)
                acc[i][j] = __builtin_amdgcn_mfma_f32_16x16x32_bf16(
                    af[i], bfv[j], acc[i][j], 0, 0, 0);
    };

    const int NT = K >> 5;                 // K/32, even

    stage(As0, Bs0);

    #define STEP(SA, SB, CA, CB, T)                                          \
    {                                                                        \
        if ((T) + 1 < NT) {                                                  \
            stage(SA, SB);                                                   \
            asm volatile("s_waitcnt vmcnt(4)" ::: "memory");                 \
        } else {                                                             \
            asm volatile("s_waitcnt vmcnt(0)" ::: "memory");                 \
        }                                                                    \
        __builtin_amdgcn_sched_barrier(0);                                   \
        __builtin_amdgcn_s_barrier();                                        \
        __builtin_amdgcn_sched_barrier(0);                                   \
        compute(CA, CB);                                                     \
        __builtin_amdgcn_sched_barrier(0);                                   \
        __builtin_amdgcn_s_barrier();                                        \
        __builtin_amdgcn_sched_barrier(0);                                   \
    }

    for (int t = 0; t < NT; t += 2) {
        STEP(As1, Bs1, As0, Bs0, t);
        STEP(As0, Bs0, As1, Bs1, t + 1);
    }
    #undef STEP

    #pragma unroll
    for (int i = 0; i < 4; ++i) {
        #pragma unroll
        for (int r = 0; r < 4; ++r) {
            const int gm = bm + wm + i * 16 + lg * 4 + r;
            #pragma unroll
            for (int j = 0; j < 4; ++j) {
                const int gn = bn + wn + j * 16 + l15;
                float v = acc[i][j][r];
                if (gn < N) {
                    if (OUTBF16)
                        ((unsigned short*)Cv)[(size_t)gm * ldc + gn] = f2b(v);
                    else
                        ((float*)Cv)[(size_t)gm * ldc + gn] = v;
                }
            }
        }
    }
}

// 64x64, 4 waves (each wave 32x32 = 2x2 frags) — Wcomb (grid 576, 2.25/CU).
// Same row layout (32-short rows), same swizzle, same STEP; 16 KiB LDS.
__global__ __launch_bounds__(256, 4) void gemm_sm(
    const unsigned short* __restrict__ A, int lda,
    const unsigned short* __restrict__ Bt, int ldb,
    unsigned short* __restrict__ Cv, int ldc, int N, int K, int nbx)
{
    __shared__ unsigned short As0[64*32], As1[64*32];
    __shared__ unsigned short Bs0[64*32], Bs1[64*32];

    const int nwg = gridDim.x;
    const int cpx = nwg >> 3;
    const int wg  = blockIdx.x;
    const int xcd = wg & 7, local = wg >> 3;
    int bmi, bni;
    if ((cpx % nbx == 0) && ((nbx & 1) == 0)) {
        const int R   = cpx / nbx;
        const int p   = local / (2 * R);
        const int idx = local % (2 * R);
        bmi = xcd * R + (idx >> 1);
        bni = p * 2 + (idx & 1);
    } else {
        const int swz = xcd * cpx + local;
        bmi = swz / nbx;
        bni = swz % nbx;
    }
    const int bm = bmi * 64;
    const int bn = bni * 64;

    const int tid  = threadIdx.x;
    const int lane = tid & 63;
    const int wave = tid >> 6;
    const int wm   = (wave >> 1) * 32;     // 0,32
    const int wn   = (wave & 1) * 32;      // 0,32
    const int l15  = lane & 15;
    const int lg   = lane >> 4;

    const int sr = tid >> 2;                               // 0..63
    const int sg = ((tid & 3) ^ ((tid >> 3) & 3)) * 8;     // swizzled src granule

    const unsigned short* pa0 = A  + (size_t)(bm + sr) * lda + sg;
    const unsigned short* pb0 = Bt + (size_t)(bn + sr) * ldb + sg;

    int aoff[2], boff[2];
    #pragma unroll
    for (int i = 0; i < 2; ++i) {
        const int tr = wm + i * 16 + l15;
        aoff[i] = tr * 64 + ((lg ^ ((tr >> 1) & 3)) << 4);
    }
    #pragma unroll
    for (int j = 0; j < 2; ++j) {
        const int tr = wn + j * 16 + l15;
        boff[j] = tr * 64 + ((lg ^ ((tr >> 1) & 3)) << 4);
    }

    floatx4 acc[2][2] = {};

    auto stage = [&](unsigned short (&SA)[64*32], unsigned short (&SB)[64*32]) {
        GLDS(pa0, (char*)SA + tid * 16);
        GLDS(pb0, (char*)SB + tid * 16);
        pa0 += 32; pb0 += 32;
    };

    auto compute = [&](const unsigned short (&CA)[64*32],
                       const unsigned short (&CB)[64*32]) {
        short8 af[2], bfv[2];
        #pragma unroll
        for (int i = 0; i < 2; ++i)
            af[i] = *(const short8*)((const char*)&CA[0] + aoff[i]);
        #pragma unroll
        for (int j = 0; j < 2; ++j)
            bfv[j] = *(const short8*)((const char*)&CB[0] + boff[j]);
        #pragma unroll
        for (int i = 0; i < 2; ++i)
            #pragma unroll
            for (int j = 0; j < 2; ++j)
                acc[i][j] = __builtin_amdgcn_mfma_f32_16x16x32_bf16(
                    af[i], bfv[j], acc[i][j], 0, 0, 0);
    };

    const int NT = K >> 5;                 // K/32, even

    stage(As0, Bs0);

    #define STEP(SA, SB, CA, CB, T)                                          \
    {                                                                        \
        if ((T) + 1 < NT) {                                                  \
            stage(SA, SB);                                                   \
            asm volatile("s_waitcnt vmcnt(2)" ::: "memory");                 \
        } else {                                                             \
            asm volatile("s_waitcnt vmcnt(0)" ::: "memory");                 \
        }                                                                    \
        __builtin_amdgcn_sched_barrier(0);                                   \
        __builtin_amdgcn_s_barrier();                                        \
        __builtin_amdgcn_sched_barrier(0);                                   \
        compute(CA, CB);                                                     \
        __builtin_amdgcn_sched_barrier(0);                                   \
        __builtin_amdgcn_s_barrier();                                        \
        __builtin_amdgcn_sched_barrier(0);                                   \
    }

    for (int t = 0; t < NT; t += 2) {
        STEP(As1, Bs1, As0, Bs0, t);
        STEP(As0, Bs0, As1, Bs1, t + 1);
    }
    #undef STEP

    #pragma unroll
    for (int i = 0; i < 2; ++i) {
        #pragma unroll
        for (int r = 0; r < 4; ++r) {
            const int gm = bm + wm + i * 16 + lg * 4 + r;
            #pragma unroll
            for (int j = 0; j < 2; ++j) {
                const int gn = bn + wn + j * 16 + l15;
                if (gn < N)
                    Cv[(size_t)gm * ldc + gn] = f2b(acc[i][j][r]);
            }
        }
    }
}

// ---------------------------------------------------------------------------
// W[K][N] f32 -> Wt[N_pad][K] bf16 (pad rows zeroed).  32x32 LDS transpose.
// ---------------------------------------------------------------------------
__global__ __launch_bounds__(256) void transpose_bf16(
    const float* __restrict__ W, unsigned short* __restrict__ Wt, int K, int N)
{
    __shared__ float t[32][33];
    const int nt = blockIdx.x * 32, kt = blockIdx.y * 32;
    const int tx = threadIdx.x & 31, ty = threadIdx.x >> 5;
    #pragma unroll
    for (int r = 0; r < 4; ++r) {
        const int k = ty + r * 8;
        const int n = nt + tx;
        float v = 0.f;
        if (n < N) v = W[(size_t)(kt + k) * N + n];
        t[k][tx] = v;
    }
    __syncthreads();
    #pragma unroll
    for (int r = 0; r < 4; ++r) {
        const int nl = ty + r * 8;
        Wt[(size_t)(nt + nl) * K + kt + tx] = f2b(t[tx][nl]);
    }
}

__global__ __launch_bounds__(256) void f32_to_bf16(
    const float* __restrict__ in, unsigned short* __restrict__ o, int n4)
{
    const int i = blockIdx.x * 256 + threadIdx.x;
    if (i >= n4) return;
    float4 v = ((const float4*)in)[i];
    ushort4 r;
    r.x = f2b(v.x); r.y = f2b(v.y); r.z = f2b(v.z); r.w = f2b(v.w);
    ((ushort4*)o)[i] = r;
}

// W_x[:, 32:] f32 (stride 1568) -> wxb[1536][1536] bf16
__global__ __launch_bounds__(256) void wx32_to_bf16(
    const float* __restrict__ Wx, unsigned short* __restrict__ o)
{
    const int i = blockIdx.x * 256 + threadIdx.x;   // over 1536*384
    if (i >= 1536 * 384) return;
    const int row = i / 384, q = i % 384;
    float4 v = *(const float4*)(Wx + (size_t)row * 1568 + 32 + q * 4);
    ushort4 r;
    r.x = f2b(v.x); r.y = f2b(v.y); r.z = f2b(v.z); r.w = f2b(v.w);
    *(ushort4*)(o + (size_t)row * 1536 + q * 4) = r;
}

// ---------------------------------------------------------------------------
// Depthwise causal conv (width 4) + bias + SiLU, 8 channels/thread, bf16.
// ---------------------------------------------------------------------------
__global__ __launch_bounds__(256) void conv_silu8(
    const unsigned short* __restrict__ xzb, const float* __restrict__ w,
    const float* __restrict__ cb, unsigned short* __restrict__ ub)
{
    const int i = blockIdx.x * 256 + threadIdx.x;    // over NROWS*192
    if (i >= NROWS * 192) return;
    const int g   = i % 192;
    const int row = i / 192;
    const int l   = row % SEQLEN;
    const int d0  = g * 8;

    short8 xr[4];
    #pragma unroll
    for (int k = 0; k < 4; ++k) {
        const int ll = l - 3 + k;
        if (ll >= 0)
            xr[k] = *(const short8*)&xzb[(size_t)(row - 3 + k) * 3072 + d0];
        else
            xr[k] = short8{0,0,0,0,0,0,0,0};
    }
    unsigned short o[8];
    #pragma unroll
    for (int e = 0; e < 8; ++e) {
        float4 we = *(const float4*)&w[(d0 + e) * 4];
        float a = cb[d0 + e];
        a = fmaf(b2f((unsigned short)xr[0][e]), we.x, a);
        a = fmaf(b2f((unsigned short)xr[1][e]), we.y, a);
        a = fmaf(b2f((unsigned short)xr[2][e]), we.z, a);
        a = fmaf(b2f((unsigned short)xr[3][e]), we.w, a);
        o[e] = f2b(a / (1.f + __expf(-a)));
    }
    *(short8*)&ub[(size_t)row * 1536 + d0] = *(short8*)o;
}

// ---------------------------------------------------------------------------
// Per-row softmax over B (16) + copy C (16) from compact xp32[row][32].
// ---------------------------------------------------------------------------
__global__ __launch_bounds__(256) void softmax_bc_kernel(
    const float* __restrict__ xp32, float* __restrict__ Bsm, float* __restrict__ Csm)
{
    const int row = blockIdx.x * 256 + threadIdx.x;
    if (row >= NROWS) return;
    const float* p = xp32 + (size_t)row * 32;
    float v[16];
    #pragma unroll
    for (int q = 0; q < 4; ++q) {
        float4 t = *(const float4*)(p + q * 4);
        v[q*4+0]=t.x; v[q*4+1]=t.y; v[q*4+2]=t.z; v[q*4+3]=t.w;
    }
    float mx = v[0];
    #pragma unroll
    for (int s = 1; s < 16; ++s) mx = fmaxf(mx, v[s]);
    float sum = 0.f;
    #pragma unroll
    for (int s = 0; s < 16; ++s) { v[s] = __expf(v[s] - mx); sum += v[s]; }
    const float inv = 1.f / sum;
    float* bo = Bsm + (size_t)row * 16;
    float* co = Csm + (size_t)row * 16;
    #pragma unroll
    for (int s = 0; s < 16; ++s) bo[s] = v[s] * inv;
    #pragma unroll
    for (int q = 0; q < 4; ++q)
        *(float4*)(co + q * 4) = *(const float4*)(p + 16 + q * 4);
}

// ---------------------------------------------------------------------------
// Scan phase A: per (b, chunk, d): chunk-final state (zero init) + dt-sum.
// ---------------------------------------------------------------------------
__global__ __launch_bounds__(256) void scan_chunk_state(
    const unsigned short* __restrict__ deltab, const unsigned short* __restrict__ ub,
    const float* __restrict__ Bsm, const float* __restrict__ A_log,
    float* __restrict__ chunkS, float* __restrict__ dtsum)
{
    const int gid = blockIdx.x * 256 + threadIdx.x;   // (b*NCHUNK+c)*D_INNER+d
    const int d = gid % D_INNER;
    const int c = (gid / D_INNER) % NCHUNK;
    const int b = gid / (D_INNER * NCHUNK);

    float A2[16];
    #pragma unroll
    for (int q = 0; q < 4; ++q) {
        float4 t = *(const float4*)(A_log + d * 16 + q * 4);
        A2[q*4+0] = -__expf(t.x) * 1.44269504089f;
        A2[q*4+1] = -__expf(t.y) * 1.44269504089f;
        A2[q*4+2] = -__expf(t.z) * 1.44269504089f;
        A2[q*4+3] = -__expf(t.w) * 1.44269504089f;
    }
    float h[16];
    #pragma unroll
    for (int s = 0; s < 16; ++s) h[s] = 0.f;
    float dts = 0.f;

    const int t0 = c * LCHUNK;
    for (int t = t0; t < t0 + LCHUNK; ++t) {
        const size_t rowoff = (size_t)b * SEQLEN + t;
        const float dt = b2f(deltab[rowoff * D_INNER + d]);
        const float uu = b2f(ub[rowoff * D_INNER + d]);
        const float du = dt * uu;
        dts += dt;
        const float4* Bp = (const float4*)(Bsm + rowoff * 16);
        float Bv[16];
        #pragma unroll
        for (int q = 0; q < 4; ++q) {
            float4 tb = Bp[q];
            Bv[q*4+0]=tb.x; Bv[q*4+1]=tb.y; Bv[q*4+2]=tb.z; Bv[q*4+3]=tb.w;
        }
        #pragma unroll
        for (int s = 0; s < 16; ++s) {
            const float dA = exp2f(dt * A2[s]);
            h[s] = fmaf(dA, h[s], du * Bv[s]);
        }
    }
    float* S = chunkS + (size_t)gid * 16;
    #pragma unroll
    for (int q = 0; q < 4; ++q)
        *(float4*)(S + q * 4) = make_float4(h[q*4+0], h[q*4+1], h[q*4+2], h[q*4+3]);
    dtsum[gid] = dts;
}

// ---------------------------------------------------------------------------
// Scan phase B: inter-chunk scan; chunkS becomes chunk-INITIAL states.
// ---------------------------------------------------------------------------
__global__ __launch_bounds__(256) void scan_chunk_scan(
    const float* __restrict__ A_log, const float* __restrict__ dtsum,
    float* __restrict__ chunkS)
{
    const int gid = blockIdx.x * 256 + threadIdx.x;   // (b*D_INNER+d)*16+s
    if (gid >= BATCH * D_INNER * 16) return;
    const int s = gid % 16;
    const int d = (gid / 16) % D_INNER;
    const int b = gid / (16 * D_INNER);
    const float A2 = -__expf(A_log[d * 16 + s]) * 1.44269504089f;
    float hprev = 0.f;
    for (int c = 0; c < NCHUNK; ++c) {
        const size_t cidx = ((size_t)(b * NCHUNK + c) * D_INNER + d);
        const float P  = exp2f(A2 * dtsum[cidx]);
        const size_t idx = cidx * 16 + s;
        const float Sc = chunkS[idx];
        chunkS[idx] = hprev;
        hprev = fmaf(P, hprev, Sc);
    }
}

// ---------------------------------------------------------------------------
// Scan phase C: re-run chunks from initial states, y = (C.h) * silu(z), bf16.
// ---------------------------------------------------------------------------
__global__ __launch_bounds__(256) void scan_output(
    const unsigned short* __restrict__ deltab, const unsigned short* __restrict__ ub,
    const float* __restrict__ Bsm, const float* __restrict__ Csm,
    const float* __restrict__ A_log, const float* __restrict__ chunkS,
    const unsigned short* __restrict__ xzb, unsigned short* __restrict__ yb)
{
    const int gid = blockIdx.x * 256 + threadIdx.x;
    const int d = gid % D_INNER;
    const int c = (gid / D_INNER) % NCHUNK;
    const int b = gid / (D_INNER * NCHUNK);

    float A2[16];
    #pragma unroll
    for (int q = 0; q < 4; ++q) {
        float4 t = *(const float4*)(A_log + d * 16 + q * 4);
        A2[q*4+0] = -__expf(t.x) * 1.44269504089f;
        A2[q*4+1] = -__expf(t.y) * 1.44269504089f;
        A2[q*4+2] = -__expf(t.z) * 1.44269504089f;
        A2[q*4+3] = -__expf(t.w) * 1.44269504089f;
    }
    float h[16];
    const float* S = chunkS + (size_t)gid * 16;
    #pragma unroll
    for (int q = 0; q < 4; ++q) {
        float4 t = *(const float4*)(S + q * 4);
        h[q*4+0]=t.x; h[q*4+1]=t.y; h[q*4+2]=t.z; h[q*4+3]=t.w;
    }

    const int t0 = c * LCHUNK;
    for (int t = t0; t < t0 + LCHUNK; ++t) {
        const size_t rowoff = (size_t)b * SEQLEN + t;
        const float dt = b2f(deltab[rowoff * D_INNER + d]);
        const float uu = b2f(ub[rowoff * D_INNER + d]);
        const float du = dt * uu;
        const float4* Bp = (const float4*)(Bsm + rowoff * 16);
        const float4* Cp = (const float4*)(Csm + rowoff * 16);
        float Bv[16], Cv[16];
        #pragma unroll
        for (int q = 0; q < 4; ++q) {
            float4 tb = Bp[q], tc = Cp[q];
            Bv[q*4+0]=tb.x; Bv[q*4+1]=tb.y; Bv[q*4+2]=tb.z; Bv[q*4+3]=tb.w;
            Cv[q*4+0]=tc.x; Cv[q*4+1]=tc.y; Cv[q*4+2]=tc.z; Cv[q*4+3]=tc.w;
        }
        float yv = 0.f;
        #pragma unroll
        for (int s = 0; s < 16; ++s) {
            const float dA = exp2f(dt * A2[s]);
            h[s] = fmaf(dA, h[s], du * Bv[s]);
            yv = fmaf(Cv[s], h[s], yv);
        }
        const float z = b2f(xzb[rowoff * (2 * D_INNER) + D_INNER + d]);
        const float sz = z / (1.f + __expf(-z));
        yb[rowoff * D_INNER + d] = f2b(yv * sz);
    }
}

// ---------------------------------------------------------------------------
extern "C" void kernel_launch(void* const* d_in, const int* in_sizes, int n_in,
                              void* d_out, int out_size, void* d_ws, size_t ws_size,
                              hipStream_t stream)
{
    const float* hs     = (const float*)d_in[0];
    const float* W_in   = (const float*)d_in[1];
    const float* conv_w = (const float*)d_in[2];
    const float* conv_b = (const float*)d_in[3];
    const float* W_x    = (const float*)d_in[4];
    const float* W_dt   = (const float*)d_in[5];
    const float* b_dt   = (const float*)d_in[6];
    const float* A_log  = (const float*)d_in[7];
    const float* W_out  = (const float*)d_in[9];
    float* out = (float*)d_out;

    // workspace layout (256B aligned)
    char* w = (char*)d_ws;
    auto alloc = [&](size_t bytes) { char* p = w; w += (bytes + 255) & ~(size_t)255; return p; };
    float*          xp32   = (float*)alloc((size_t)NROWS * 32 * 4);
    unsigned short* deltab = (unsigned short*)alloc((size_t)NROWS * 1536 * 2);
    float*          Bsm    = (float*)alloc((size_t)NROWS * 16 * 4);
    float*          Csm    = (float*)alloc((size_t)NROWS * 16 * 4);
    float*          chunkS = (float*)alloc((size_t)BATCH * NCHUNK * D_INNER * 16 * 4);
    float*          dtsum  = (float*)alloc((size_t)BATCH * NCHUNK * D_INNER * 4);
    unsigned short* xzb    = (unsigned short*)alloc((size_t)NROWS * 3072 * 2);
    unsigned short* ub     = (unsigned short*)alloc((size_t)NROWS * 1536 * 2);
    unsigned short* yb     = (unsigned short*)alloc((size_t)NROWS * 1536 * 2);
    unsigned short* hsb    = (unsigned short*)alloc((size_t)NROWS * 768 * 2);
    unsigned short* Wt_in  = (unsigned short*)alloc((size_t)3072 * 768 * 2);
    unsigned short* Wt_x   = (unsigned short*)alloc((size_t)1792 * 1536 * 2);
    unsigned short* Wt_dt  = (unsigned short*)alloc((size_t)1536 * 1536 * 2);
    unsigned short* Wt_out = (unsigned short*)alloc((size_t)768 * 1536 * 2);
    unsigned short* wxb    = (unsigned short*)alloc((size_t)1536 * 1536 * 2);

    const dim3 blk(256);

    // 0) weight transposes + converts
    transpose_bf16<<<dim3(3072/32, 768/32),  blk, 0, stream>>>(W_in,  Wt_in,  768,  3072);
    transpose_bf16<<<dim3(1792/32, 1536/32), blk, 0, stream>>>(W_x,   Wt_x,   1536, 1568);
    transpose_bf16<<<dim3(1536/32, 1536/32), blk, 0, stream>>>(W_dt,  Wt_dt,  1536, 1536);
    transpose_bf16<<<dim3(768/32,  1536/32), blk, 0, stream>>>(W_out, Wt_out, 1536, 768);
    f32_to_bf16<<<(NROWS*768/4 + 255)/256, blk, 0, stream>>>(hs, hsb, NROWS*768/4);
    wx32_to_bf16<<<(1536*384 + 255)/256, blk, 0, stream>>>(W_x, wxb);

    // 0b) W_comb^T = (W_x[:,32:] @ W_dt)^T spliced into Wt_x rows 32..1567:
    //     [M=1536, N=1536, K=1536; 64^2 tile; grid 24*24=576, 2.25 blocks/CU]
    gemm_sm<<<dim3(576), blk, 0, stream>>>(
        Wt_dt, 1536, wxb, 1536, Wt_x + (size_t)32 * 1536, 1536, 1536, 1536, 24);

    // 1) xz = hs @ W_in  (bf16 out)  [256x128 8-wave; K=768; grid 32*24=768]
    gemm_w8<0,1><<<dim3(768), dim3(512), 0, stream>>>(
        hsb, 768, Wt_in, 768, xzb, 3072, nullptr, 3072, 768, nullptr, 24);

    // 2) u = silu(conv(x) + cb)
    conv_silu8<<<(NROWS*192)/256, blk, 0, stream>>>(xzb, conv_w, conv_b, ub);

    // 3) fused xp+delta GEMM: u @ [W_x[:,:32] | W_comb]
    //    [256x128 8-wave; K=1536; grid 32*13=416, %8==0]
    gemm_w8<3,0><<<dim3(416), dim3(512), 0, stream>>>(
        ub, 1536, Wt_x, 1536, deltab, 1536, xp32, 1568, 1536, b_dt, 13);

    // 4) Bsm = softmax(xp32[:, :16]), Csm = xp32[:, 16:32]
    softmax_bc_kernel<<<NROWS/256, blk, 0, stream>>>(xp32, Bsm, Csm);

    // 5-7) chunked selective scan (NCHUNK=128: 1536 blocks for A/C)
    scan_chunk_state<<<(BATCH*NCHUNK*D_INNER)/256, blk, 0, stream>>>(
        deltab, ub, Bsm, A_log, chunkS, dtsum);
    scan_chunk_scan<<<(BATCH*D_INNER*16 + 255)/256, blk, 0, stream>>>(
        A_log, dtsum, chunkS);
    scan_output<<<(BATCH*NCHUNK*D_INNER)/256, blk, 0, stream>>>(
        deltab, ub, Bsm, Csm, A_log, chunkS, xzb, yb);

    // 8) out = y @ W_out  (f32 out)  [128^2; grid 6*64=384, %8==0]
    gemm_p2<0,0><<<dim3(384), blk, 0, stream>>>(
        yb, 1536, Wt_out, 1536, out, 768, nullptr, 768, 1536, nullptr, 6);
}

// Round 18
// 444.655 us; speedup vs baseline: 1.1971x; 1.0029x over previous
//
#include <hip/hip_runtime.h>
#include <hip/hip_bf16.h>
#include <math.h>

#define D_MODEL 768
#define D_STATE 16
#define D_CONVW 4
#define D_INNER 1536
#define BATCH   2
#define SEQLEN  4096
#define NROWS   (BATCH*SEQLEN)       // 8192
#define NCHUNK  128                  // scan TLP: 1536 blocks for phases A/C
#define LCHUNK  (SEQLEN/NCHUNK)      // 32

typedef __attribute__((ext_vector_type(8))) short short8;
typedef __attribute__((ext_vector_type(4))) float floatx4;

__device__ inline unsigned short f2b(float x) {
    unsigned u = __float_as_uint(x);
    return (unsigned short)((u + 0x7fffu + ((u >> 16) & 1u)) >> 16);   // RNE
}
__device__ inline float b2f(unsigned short b) {
    return __uint_as_float(((unsigned)b) << 16);
}

#define GLDS(gp, lp) __builtin_amdgcn_global_load_lds( \
    (const __attribute__((address_space(1))) void*)(gp), \
    (__attribute__((address_space(3))) void*)(lp), 16, 0, 0)

// ---------------------------------------------------------------------------
// r18 = r14 best config (442.65us) + conv 4-rows/thread sliding window.
// GEMM plateau note (r4..r17): all structural levers (schedule, pipeline
// depth, swizzle, tile geometry, barrier count, de-VALU) bracketed at the
// same ~340 TF shape-curve ceiling; 256^2/8-phase inapplicable (N too small
// to fill grid at 1 block/CU).  Keep small-LDS multi-block-residency kernels.
// ---------------------------------------------------------------------------

// 256x128 (MxN), 8 waves.  Grid 1D = nbx*(M/256), %8==0.  NT=K/32 even.
// EPI: 0 plain (OUTBF16 sel), 3 fused xp+delta (gn<32 -> f32 C2,
//      else softplus(acc+bias[gn-32]) -> bf16 Cv).
template<int EPI, int OUTBF16>
__global__ __launch_bounds__(512, 4) void gemm_w8(
    const unsigned short* __restrict__ A, int lda,
    const unsigned short* __restrict__ Bt, int ldb,
    void* __restrict__ Cv, int ldc, float* __restrict__ C2,
    int N, int K, const float* __restrict__ bias, int nbx)
{
    __shared__ unsigned short As0[256*32], As1[256*32];
    __shared__ unsigned short Bs0[128*32], Bs1[128*32];

    const int nwg = gridDim.x;
    const int cpx = nwg >> 3;
    const int wg  = blockIdx.x;
    const int xcd = wg & 7, local = wg >> 3;
    int bmi, bni;
    if ((cpx % nbx == 0) && ((nbx & 1) == 0)) {
        const int R   = cpx / nbx;
        const int p   = local / (2 * R);
        const int idx = local % (2 * R);
        bmi = xcd * R + (idx >> 1);
        bni = p * 2 + (idx & 1);
    } else {
        const int swz = xcd * cpx + local;
        bmi = swz / nbx;
        bni = swz % nbx;
    }
    const int bm = bmi * 256;
    const int bn = bni * 128;

    const int tid  = threadIdx.x;          // 0..511
    const int lane = tid & 63;
    const int wave = tid >> 6;             // 0..7
    const int wm   = (wave >> 1) * 64;     // 0,64,128,192
    const int wn   = (wave & 1) * 64;      // 0,64
    const int l15  = lane & 15;
    const int lg   = lane >> 4;

    const int sr    = tid >> 2;                              // 0..127
    const int sg    = ((tid & 3) ^ ((tid >> 3) & 3)) * 8;    // swizzled src granule
    const int lbase = (tid & ~63) * 16;                      // wave-uniform LDS base

    const unsigned short* pa0 = A  + (size_t)(bm + sr) * lda + sg;
    const unsigned short* pa1 = A  + (size_t)(bm + 128 + sr) * lda + sg;
    const unsigned short* pb0 = Bt + (size_t)(bn + sr) * ldb + sg;

    int aoff[4], boff[4];
    #pragma unroll
    for (int i = 0; i < 4; ++i) {
        const int tr = wm + i * 16 + l15;
        aoff[i] = tr * 64 + ((lg ^ ((tr >> 1) & 3)) << 4);
    }
    #pragma unroll
    for (int j = 0; j < 4; ++j) {
        const int tr = wn + j * 16 + l15;
        boff[j] = tr * 64 + ((lg ^ ((tr >> 1) & 3)) << 4);
    }

    floatx4 acc[4][4] = {};

    auto stage = [&](unsigned short (&SA)[256*32], unsigned short (&SB)[128*32]) {
        GLDS(pa0, (char*)SA + lbase);
        GLDS(pa1, (char*)SA + 8192 + lbase);
        GLDS(pb0, (char*)SB + lbase);
        pa0 += 32; pa1 += 32; pb0 += 32;
    };

    auto compute = [&](const unsigned short (&CA)[256*32],
                       const unsigned short (&CB)[128*32]) {
        short8 af[4], bfv[4];
        #pragma unroll
        for (int i = 0; i < 4; ++i)
            af[i] = *(const short8*)((const char*)&CA[0] + aoff[i]);
        #pragma unroll
        for (int j = 0; j < 4; ++j)
            bfv[j] = *(const short8*)((const char*)&CB[0] + boff[j]);
        #pragma unroll
        for (int i = 0; i < 4; ++i)
            #pragma unroll
            for (int j = 0; j < 4; ++j)
                acc[i][j] = __builtin_amdgcn_mfma_f32_16x16x32_bf16(
                    af[i], bfv[j], acc[i][j], 0, 0, 0);
    };

    const int NT = K >> 5;                 // K/32, even

    stage(As0, Bs0);                       // prologue: tile 0 -> buf0

    #define STEP(SA, SB, CA, CB, T)                                          \
    {                                                                        \
        if ((T) + 1 < NT) {                                                  \
            stage(SA, SB);                                                   \
            asm volatile("s_waitcnt vmcnt(3)" ::: "memory");                 \
        } else {                                                             \
            asm volatile("s_waitcnt vmcnt(0)" ::: "memory");                 \
        }                                                                    \
        __builtin_amdgcn_sched_barrier(0);                                   \
        __builtin_amdgcn_s_barrier();                                        \
        __builtin_amdgcn_sched_barrier(0);                                   \
        compute(CA, CB);                                                     \
        __builtin_amdgcn_sched_barrier(0);                                   \
        __builtin_amdgcn_s_barrier();                                        \
        __builtin_amdgcn_sched_barrier(0);                                   \
    }

    for (int t = 0; t < NT; t += 2) {
        STEP(As1, Bs1, As0, Bs0, t);
        STEP(As0, Bs0, As1, Bs1, t + 1);
    }
    #undef STEP

    // C/D layout: col = lane&15, row = (lane>>4)*4 + reg  (m89-verified)
    #pragma unroll
    for (int i = 0; i < 4; ++i) {
        #pragma unroll
        for (int r = 0; r < 4; ++r) {
            const int gm = bm + wm + i * 16 + lg * 4 + r;
            #pragma unroll
            for (int j = 0; j < 4; ++j) {
                const int gn = bn + wn + j * 16 + l15;
                float v = acc[i][j][r];
                if (EPI == 3) {
                    if (gn < 32) {
                        C2[(size_t)gm * 32 + gn] = v;
                    } else if (gn < N) {
                        v += bias[gn - 32];
                        v = (v > 20.f) ? v : log1pf(__expf(v));
                        ((unsigned short*)Cv)[(size_t)gm * 1536 + gn - 32] = f2b(v);
                    }
                } else {
                    if (gn < N) {
                        if (OUTBF16)
                            ((unsigned short*)Cv)[(size_t)gm * ldc + gn] = f2b(v);
                        else
                            ((float*)Cv)[(size_t)gm * ldc + gn] = v;
                    }
                }
            }
        }
    }
}

// 128x128, 4 waves — Wcomb (144 blocks) and out-proj (384 blocks).
template<int EPI, int OUTBF16>
__global__ __launch_bounds__(256, 4) void gemm_p2(
    const unsigned short* __restrict__ A, int lda,
    const unsigned short* __restrict__ Bt, int ldb,
    void* __restrict__ Cv, int ldc, float* __restrict__ C2,
    int N, int K, const float* __restrict__ bias, int nbx)
{
    __shared__ unsigned short As0[128*32], As1[128*32];
    __shared__ unsigned short Bs0[128*32], Bs1[128*32];

    const int nwg = gridDim.x;
    const int cpx = nwg >> 3;
    const int wg  = blockIdx.x;
    const int xcd = wg & 7, local = wg >> 3;
    int bmi, bni;
    if ((cpx % nbx == 0) && ((nbx & 1) == 0)) {
        const int R   = cpx / nbx;
        const int p   = local / (2 * R);
        const int idx = local % (2 * R);
        bmi = xcd * R + (idx >> 1);
        bni = p * 2 + (idx & 1);
    } else {
        const int swz = xcd * cpx + local;
        bmi = swz / nbx;
        bni = swz % nbx;
    }
    const int bm = bmi * 128;
    const int bn = bni * 128;

    const int tid  = threadIdx.x;
    const int lane = tid & 63;
    const int wave = tid >> 6;
    const int wm   = (wave >> 1) * 64;
    const int wn   = (wave & 1) * 64;
    const int l15  = lane & 15;
    const int lg   = lane >> 4;

    const int sr    = tid >> 2;
    const int sg    = ((tid & 3) ^ ((tid >> 3) & 3)) * 8;
    const int lbase = (tid & ~63) * 16;

    const unsigned short* pa0 = A  + (size_t)(bm + sr) * lda + sg;
    const unsigned short* pa1 = A  + (size_t)(bm + 64 + sr) * lda + sg;
    const unsigned short* pb0 = Bt + (size_t)(bn + sr) * ldb + sg;
    const unsigned short* pb1 = Bt + (size_t)(bn + 64 + sr) * ldb + sg;

    int aoff[4], boff[4];
    #pragma unroll
    for (int i = 0; i < 4; ++i) {
        const int tr = wm + i * 16 + l15;
        aoff[i] = tr * 64 + ((lg ^ ((tr >> 1) & 3)) << 4);
    }
    #pragma unroll
    for (int j = 0; j < 4; ++j) {
        const int tr = wn + j * 16 + l15;
        boff[j] = tr * 64 + ((lg ^ ((tr >> 1) & 3)) << 4);
    }

    floatx4 acc[4][4] = {};

    auto stage = [&](unsigned short (&SA)[128*32], unsigned short (&SB)[128*32]) {
        GLDS(pa0, (char*)SA + lbase);
        GLDS(pa1, (char*)SA + 4096 + lbase);
        GLDS(pb0, (char*)SB + lbase);
        GLDS(pb1, (char*)SB + 4096 + lbase);
        pa0 += 32; pa1 += 32; pb0 += 32; pb1 += 32;
    };

    auto compute = [&](const unsigned short (&CA)[128*32],
                       const unsigned short (&CB)[128*32]) {
        short8 af[4], bfv[4];
        #pragma unroll
        for (int i = 0; i < 4; ++i)
            af[i] = *(const short8*)((const char*)&CA[0] + aoff[i]);
        #pragma unroll
        for (int j = 0; j < 4; ++j)
            bfv[j] = *(const short8*)((const char*)&CB[0] + boff[j]);
        #pragma unroll
        for (int i = 0; i < 4; ++i)
            #pragma unroll
            for (int j = 0; j < 4; ++j)
                acc[i][j] = __builtin_amdgcn_mfma_f32_16x16x32_bf16(
                    af[i], bfv[j], acc[i][j], 0, 0, 0);
    };

    const int NT = K >> 5;                 // K/32, even

    stage(As0, Bs0);

    #define STEP(SA, SB, CA, CB, T)                                          \
    {                                                                        \
        if ((T) + 1 < NT) {                                                  \
            stage(SA, SB);                                                   \
            asm volatile("s_waitcnt vmcnt(4)" ::: "memory");                 \
        } else {                                                             \
            asm volatile("s_waitcnt vmcnt(0)" ::: "memory");                 \
        }                                                                    \
        __builtin_amdgcn_sched_barrier(0);                                   \
        __builtin_amdgcn_s_barrier();                                        \
        __builtin_amdgcn_sched_barrier(0);                                   \
        compute(CA, CB);                                                     \
        __builtin_amdgcn_sched_barrier(0);                                   \
        __builtin_amdgcn_s_barrier();                                        \
        __builtin_amdgcn_sched_barrier(0);                                   \
    }

    for (int t = 0; t < NT; t += 2) {
        STEP(As1, Bs1, As0, Bs0, t);
        STEP(As0, Bs0, As1, Bs1, t + 1);
    }
    #undef STEP

    #pragma unroll
    for (int i = 0; i < 4; ++i) {
        #pragma unroll
        for (int r = 0; r < 4; ++r) {
            const int gm = bm + wm + i * 16 + lg * 4 + r;
            #pragma unroll
            for (int j = 0; j < 4; ++j) {
                const int gn = bn + wn + j * 16 + l15;
                float v = acc[i][j][r];
                if (gn < N) {
                    if (OUTBF16)
                        ((unsigned short*)Cv)[(size_t)gm * ldc + gn] = f2b(v);
                    else
                        ((float*)Cv)[(size_t)gm * ldc + gn] = v;
                }
            }
        }
    }
}

// ---------------------------------------------------------------------------
// W[K][N] f32 -> Wt[N_pad][K] bf16 (pad rows zeroed).  32x32 LDS transpose.
// ---------------------------------------------------------------------------
__global__ __launch_bounds__(256) void transpose_bf16(
    const float* __restrict__ W, unsigned short* __restrict__ Wt, int K, int N)
{
    __shared__ float t[32][33];
    const int nt = blockIdx.x * 32, kt = blockIdx.y * 32;
    const int tx = threadIdx.x & 31, ty = threadIdx.x >> 5;
    #pragma unroll
    for (int r = 0; r < 4; ++r) {
        const int k = ty + r * 8;
        const int n = nt + tx;
        float v = 0.f;
        if (n < N) v = W[(size_t)(kt + k) * N + n];
        t[k][tx] = v;
    }
    __syncthreads();
    #pragma unroll
    for (int r = 0; r < 4; ++r) {
        const int nl = ty + r * 8;
        Wt[(size_t)(nt + nl) * K + kt + tx] = f2b(t[tx][nl]);
    }
}

__global__ __launch_bounds__(256) void f32_to_bf16(
    const float* __restrict__ in, unsigned short* __restrict__ o, int n4)
{
    const int i = blockIdx.x * 256 + threadIdx.x;
    if (i >= n4) return;
    float4 v = ((const float4*)in)[i];
    ushort4 r;
    r.x = f2b(v.x); r.y = f2b(v.y); r.z = f2b(v.z); r.w = f2b(v.w);
    ((ushort4*)o)[i] = r;
}

// W_x[:, 32:] f32 (stride 1568) -> wxb[1536][1536] bf16
__global__ __launch_bounds__(256) void wx32_to_bf16(
    const float* __restrict__ Wx, unsigned short* __restrict__ o)
{
    const int i = blockIdx.x * 256 + threadIdx.x;   // over 1536*384
    if (i >= 1536 * 384) return;
    const int row = i / 384, q = i % 384;
    float4 v = *(const float4*)(Wx + (size_t)row * 1568 + 32 + q * 4);
    ushort4 r;
    r.x = f2b(v.x); r.y = f2b(v.y); r.z = f2b(v.z); r.w = f2b(v.w);
    *(ushort4*)(o + (size_t)row * 1536 + q * 4) = r;
}

// ---------------------------------------------------------------------------
// Depthwise causal conv (width 4) + bias + SiLU — 4 rows x 8 channels per
// thread, sliding window: 7 row-loads for 4 outputs (1.75x read amp vs 4x),
// weights/bias loaded once per 4 outputs.  Math per output identical to r17.
// ---------------------------------------------------------------------------
__global__ __launch_bounds__(256) void conv_silu4r(
    const unsigned short* __restrict__ xzb, const float* __restrict__ w,
    const float* __restrict__ cb, unsigned short* __restrict__ ub)
{
    const int i = blockIdx.x * 256 + threadIdx.x;    // over (NROWS/4)*192
    if (i >= (NROWS / 4) * 192) return;
    const int g    = i % 192;
    const int rowq = i / 192;
    const int row0 = rowq * 4;                 // global row (4-aligned)
    const int lb   = row0 % SEQLEN;            // within-sequence position
    const int d0   = g * 8;

    float4 we[8];
    float  cbv[8];
    #pragma unroll
    for (int e = 0; e < 8; ++e) {
        we[e]  = *(const float4*)&w[(d0 + e) * 4];
        cbv[e] = cb[d0 + e];
    }

    short8 xr[7];
    #pragma unroll
    for (int k = 0; k < 7; ++k) {
        const int ll = lb - 3 + k;             // rows row0-3 .. row0+3
        if (ll >= 0)
            xr[k] = *(const short8*)&xzb[(size_t)(row0 - 3 + k) * 3072 + d0];
        else
            xr[k] = short8{0,0,0,0,0,0,0,0};
    }

    #pragma unroll
    for (int r = 0; r < 4; ++r) {
        unsigned short o[8];
        #pragma unroll
        for (int e = 0; e < 8; ++e) {
            float a = cbv[e];
            a = fmaf(b2f((unsigned short)xr[r + 0][e]), we[e].x, a);
            a = fmaf(b2f((unsigned short)xr[r + 1][e]), we[e].y, a);
            a = fmaf(b2f((unsigned short)xr[r + 2][e]), we[e].z, a);
            a = fmaf(b2f((unsigned short)xr[r + 3][e]), we[e].w, a);
            o[e] = f2b(a / (1.f + __expf(-a)));
        }
        *(short8*)&ub[(size_t)(row0 + r) * 1536 + d0] = *(short8*)o;
    }
}

// ---------------------------------------------------------------------------
// Per-row softmax over B (16) + copy C (16) from compact xp32[row][32].
// ---------------------------------------------------------------------------
__global__ __launch_bounds__(256) void softmax_bc_kernel(
    const float* __restrict__ xp32, float* __restrict__ Bsm, float* __restrict__ Csm)
{
    const int row = blockIdx.x * 256 + threadIdx.x;
    if (row >= NROWS) return;
    const float* p = xp32 + (size_t)row * 32;
    float v[16];
    #pragma unroll
    for (int q = 0; q < 4; ++q) {
        float4 t = *(const float4*)(p + q * 4);
        v[q*4+0]=t.x; v[q*4+1]=t.y; v[q*4+2]=t.z; v[q*4+3]=t.w;
    }
    float mx = v[0];
    #pragma unroll
    for (int s = 1; s < 16; ++s) mx = fmaxf(mx, v[s]);
    float sum = 0.f;
    #pragma unroll
    for (int s = 0; s < 16; ++s) { v[s] = __expf(v[s] - mx); sum += v[s]; }
    const float inv = 1.f / sum;
    float* bo = Bsm + (size_t)row * 16;
    float* co = Csm + (size_t)row * 16;
    #pragma unroll
    for (int s = 0; s < 16; ++s) bo[s] = v[s] * inv;
    #pragma unroll
    for (int q = 0; q < 4; ++q)
        *(float4*)(co + q * 4) = *(const float4*)(p + 16 + q * 4);
}

// ---------------------------------------------------------------------------
// Scan phase A: per (b, chunk, d): chunk-final state (zero init) + dt-sum.
// ---------------------------------------------------------------------------
__global__ __launch_bounds__(256) void scan_chunk_state(
    const unsigned short* __restrict__ deltab, const unsigned short* __restrict__ ub,
    const float* __restrict__ Bsm, const float* __restrict__ A_log,
    float* __restrict__ chunkS, float* __restrict__ dtsum)
{
    const int gid = blockIdx.x * 256 + threadIdx.x;   // (b*NCHUNK+c)*D_INNER+d
    const int d = gid % D_INNER;
    const int c = (gid / D_INNER) % NCHUNK;
    const int b = gid / (D_INNER * NCHUNK);

    float A2[16];
    #pragma unroll
    for (int q = 0; q < 4; ++q) {
        float4 t = *(const float4*)(A_log + d * 16 + q * 4);
        A2[q*4+0] = -__expf(t.x) * 1.44269504089f;
        A2[q*4+1] = -__expf(t.y) * 1.44269504089f;
        A2[q*4+2] = -__expf(t.z) * 1.44269504089f;
        A2[q*4+3] = -__expf(t.w) * 1.44269504089f;
    }
    float h[16];
    #pragma unroll
    for (int s = 0; s < 16; ++s) h[s] = 0.f;
    float dts = 0.f;

    const int t0 = c * LCHUNK;
    for (int t = t0; t < t0 + LCHUNK; ++t) {
        const size_t rowoff = (size_t)b * SEQLEN + t;
        const float dt = b2f(deltab[rowoff * D_INNER + d]);
        const float uu = b2f(ub[rowoff * D_INNER + d]);
        const float du = dt * uu;
        dts += dt;
        const float4* Bp = (const float4*)(Bsm + rowoff * 16);
        float Bv[16];
        #pragma unroll
        for (int q = 0; q < 4; ++q) {
            float4 tb = Bp[q];
            Bv[q*4+0]=tb.x; Bv[q*4+1]=tb.y; Bv[q*4+2]=tb.z; Bv[q*4+3]=tb.w;
        }
        #pragma unroll
        for (int s = 0; s < 16; ++s) {
            const float dA = exp2f(dt * A2[s]);
            h[s] = fmaf(dA, h[s], du * Bv[s]);
        }
    }
    float* S = chunkS + (size_t)gid * 16;
    #pragma unroll
    for (int q = 0; q < 4; ++q)
        *(float4*)(S + q * 4) = make_float4(h[q*4+0], h[q*4+1], h[q*4+2], h[q*4+3]);
    dtsum[gid] = dts;
}

// ---------------------------------------------------------------------------
// Scan phase B: inter-chunk scan; chunkS becomes chunk-INITIAL states.
// ---------------------------------------------------------------------------
__global__ __launch_bounds__(256) void scan_chunk_scan(
    const float* __restrict__ A_log, const float* __restrict__ dtsum,
    float* __restrict__ chunkS)
{
    const int gid = blockIdx.x * 256 + threadIdx.x;   // (b*D_INNER+d)*16+s
    if (gid >= BATCH * D_INNER * 16) return;
    const int s = gid % 16;
    const int d = (gid / 16) % D_INNER;
    const int b = gid / (16 * D_INNER);
    const float A2 = -__expf(A_log[d * 16 + s]) * 1.44269504089f;
    float hprev = 0.f;
    for (int c = 0; c < NCHUNK; ++c) {
        const size_t cidx = ((size_t)(b * NCHUNK + c) * D_INNER + d);
        const float P  = exp2f(A2 * dtsum[cidx]);
        const size_t idx = cidx * 16 + s;
        const float Sc = chunkS[idx];
        chunkS[idx] = hprev;
        hprev = fmaf(P, hprev, Sc);
    }
}

// ---------------------------------------------------------------------------
// Scan phase C: re-run chunks from initial states, y = (C.h) * silu(z), bf16.
// ---------------------------------------------------------------------------
__global__ __launch_bounds__(256) void scan_output(
    const unsigned short* __restrict__ deltab, const unsigned short* __restrict__ ub,
    const float* __restrict__ Bsm, const float* __restrict__ Csm,
    const float* __restrict__ A_log, const float* __restrict__ chunkS,
    const unsigned short* __restrict__ xzb, unsigned short* __restrict__ yb)
{
    const int gid = blockIdx.x * 256 + threadIdx.x;
    const int d = gid % D_INNER;
    const int c = (gid / D_INNER) % NCHUNK;
    const int b = gid / (D_INNER * NCHUNK);

    float A2[16];
    #pragma unroll
    for (int q = 0; q < 4; ++q) {
        float4 t = *(const float4*)(A_log + d * 16 + q * 4);
        A2[q*4+0] = -__expf(t.x) * 1.44269504089f;
        A2[q*4+1] = -__expf(t.y) * 1.44269504089f;
        A2[q*4+2] = -__expf(t.z) * 1.44269504089f;
        A2[q*4+3] = -__expf(t.w) * 1.44269504089f;
    }
    float h[16];
    const float* S = chunkS + (size_t)gid * 16;
    #pragma unroll
    for (int q = 0; q < 4; ++q) {
        float4 t = *(const float4*)(S + q * 4);
        h[q*4+0]=t.x; h[q*4+1]=t.y; h[q*4+2]=t.z; h[q*4+3]=t.w;
    }

    const int t0 = c * LCHUNK;
    for (int t = t0; t < t0 + LCHUNK; ++t) {
        const size_t rowoff = (size_t)b * SEQLEN + t;
        const float dt = b2f(deltab[rowoff * D_INNER + d]);
        const float uu = b2f(ub[rowoff * D_INNER + d]);
        const float du = dt * uu;
        const float4* Bp = (const float4*)(Bsm + rowoff * 16);
        const float4* Cp = (const float4*)(Csm + rowoff * 16);
        float Bv[16], Cv[16];
        #pragma unroll
        for (int q = 0; q < 4; ++q) {
            float4 tb = Bp[q], tc = Cp[q];
            Bv[q*4+0]=tb.x; Bv[q*4+1]=tb.y; Bv[q*4+2]=tb.z; Bv[q*4+3]=tb.w;
            Cv[q*4+0]=tc.x; Cv[q*4+1]=tc.y; Cv[q*4+2]=tc.z; Cv[q*4+3]=tc.w;
        }
        float yv = 0.f;
        #pragma unroll
        for (int s = 0; s < 16; ++s) {
            const float dA = exp2f(dt * A2[s]);
            h[s] = fmaf(dA, h[s], du * Bv[s]);
            yv = fmaf(Cv[s], h[s], yv);
        }
        const float z = b2f(xzb[rowoff * (2 * D_INNER) + D_INNER + d]);
        const float sz = z / (1.f + __expf(-z));
        yb[rowoff * D_INNER + d] = f2b(yv * sz);
    }
}

// ---------------------------------------------------------------------------
extern "C" void kernel_launch(void* const* d_in, const int* in_sizes, int n_in,
                              void* d_out, int out_size, void* d_ws, size_t ws_size,
                              hipStream_t stream)
{
    const float* hs     = (const float*)d_in[0];
    const float* W_in   = (const float*)d_in[1];
    const float* conv_w = (const float*)d_in[2];
    const float* conv_b = (const float*)d_in[3];
    const float* W_x    = (const float*)d_in[4];
    const float* W_dt   = (const float*)d_in[5];
    const float* b_dt   = (const float*)d_in[6];
    const float* A_log  = (const float*)d_in[7];
    const float* W_out  = (const float*)d_in[9];
    float* out = (float*)d_out;

    // workspace layout (256B aligned)
    char* w = (char*)d_ws;
    auto alloc = [&](size_t bytes) { char* p = w; w += (bytes + 255) & ~(size_t)255; return p; };
    float*          xp32   = (float*)alloc((size_t)NROWS * 32 * 4);
    unsigned short* deltab = (unsigned short*)alloc((size_t)NROWS * 1536 * 2);
    float*          Bsm    = (float*)alloc((size_t)NROWS * 16 * 4);
    float*          Csm    = (float*)alloc((size_t)NROWS * 16 * 4);
    float*          chunkS = (float*)alloc((size_t)BATCH * NCHUNK * D_INNER * 16 * 4);
    float*          dtsum  = (float*)alloc((size_t)BATCH * NCHUNK * D_INNER * 4);
    unsigned short* xzb    = (unsigned short*)alloc((size_t)NROWS * 3072 * 2);
    unsigned short* ub     = (unsigned short*)alloc((size_t)NROWS * 1536 * 2);
    unsigned short* yb     = (unsigned short*)alloc((size_t)NROWS * 1536 * 2);
    unsigned short* hsb    = (unsigned short*)alloc((size_t)NROWS * 768 * 2);
    unsigned short* Wt_in  = (unsigned short*)alloc((size_t)3072 * 768 * 2);
    unsigned short* Wt_x   = (unsigned short*)alloc((size_t)1792 * 1536 * 2);
    unsigned short* Wt_dt  = (unsigned short*)alloc((size_t)1536 * 1536 * 2);
    unsigned short* Wt_out = (unsigned short*)alloc((size_t)768 * 1536 * 2);
    unsigned short* wxb    = (unsigned short*)alloc((size_t)1536 * 1536 * 2);

    const dim3 blk(256);

    // 0) weight transposes + converts
    transpose_bf16<<<dim3(3072/32, 768/32),  blk, 0, stream>>>(W_in,  Wt_in,  768,  3072);
    transpose_bf16<<<dim3(1792/32, 1536/32), blk, 0, stream>>>(W_x,   Wt_x,   1536, 1568);
    transpose_bf16<<<dim3(1536/32, 1536/32), blk, 0, stream>>>(W_dt,  Wt_dt,  1536, 1536);
    transpose_bf16<<<dim3(768/32,  1536/32), blk, 0, stream>>>(W_out, Wt_out, 1536, 768);
    f32_to_bf16<<<(NROWS*768/4 + 255)/256, blk, 0, stream>>>(hs, hsb, NROWS*768/4);
    wx32_to_bf16<<<(1536*384 + 255)/256, blk, 0, stream>>>(W_x, wxb);

    // 0b) W_comb^T = (W_x[:,32:] @ W_dt)^T spliced into Wt_x rows 32..1567:
    //     [M=1536, N=1536, K=1536; 128^2 kernel; grid 144]
    gemm_p2<0,1><<<dim3(144), blk, 0, stream>>>(
        Wt_dt, 1536, wxb, 1536, Wt_x + (size_t)32 * 1536, 1536, nullptr,
        1536, 1536, nullptr, 12);

    // 1) xz = hs @ W_in  (bf16 out)  [256x128 8-wave; K=768; grid 32*24=768]
    gemm_w8<0,1><<<dim3(768), dim3(512), 0, stream>>>(
        hsb, 768, Wt_in, 768, xzb, 3072, nullptr, 3072, 768, nullptr, 24);

    // 2) u = silu(conv(x) + cb)  [4 rows/thread sliding window]
    conv_silu4r<<<((NROWS/4)*192)/256, blk, 0, stream>>>(xzb, conv_w, conv_b, ub);

    // 3) fused xp+delta GEMM: u @ [W_x[:,:32] | W_comb]
    //    [256x128 8-wave; K=1536; grid 32*13=416, %8==0]
    gemm_w8<3,0><<<dim3(416), dim3(512), 0, stream>>>(
        ub, 1536, Wt_x, 1536, deltab, 1536, xp32, 1568, 1536, b_dt, 13);

    // 4) Bsm = softmax(xp32[:, :16]), Csm = xp32[:, 16:32]
    softmax_bc_kernel<<<NROWS/256, blk, 0, stream>>>(xp32, Bsm, Csm);

    // 5-7) chunked selective scan (NCHUNK=128: 1536 blocks for A/C)
    scan_chunk_state<<<(BATCH*NCHUNK*D_INNER)/256, blk, 0, stream>>>(
        deltab, ub, Bsm, A_log, chunkS, dtsum);
    scan_chunk_scan<<<(BATCH*D_INNER*16 + 255)/256, blk, 0, stream>>>(
        A_log, dtsum, chunkS);
    scan_output<<<(BATCH*NCHUNK*D_INNER)/256, blk, 0, stream>>>(
        deltab, ub, Bsm, Csm, A_log, chunkS, xzb, yb);

    // 8) out = y @ W_out  (f32 out)  [128^2; grid 6*64=384, %8==0]
    gemm_p2<0,0><<<dim3(384), blk, 0, stream>>>(
        yb, 1536, Wt_out, 1536, out, 768, nullptr, 768, 1536, nullptr, 6);
}

// Round 19
// 408.780 us; speedup vs baseline: 1.3021x; 1.0878x over previous
//
#include <hip/hip_runtime.h>
#include <hip/hip_bf16.h>
#include <math.h>

#define D_MODEL 768
#define D_STATE 16
#define D_CONVW 4
#define D_INNER 1536
#define BATCH   2
#define SEQLEN  4096
#define NROWS   (BATCH*SEQLEN)       // 8192
#define NCHUNK  128                  // scan TLP: 1536 blocks for phases A/C
#define LCHUNK  (SEQLEN/NCHUNK)      // 32

typedef __attribute__((ext_vector_type(8))) short short8;
typedef __attribute__((ext_vector_type(4))) float floatx4;

__device__ inline unsigned short f2b(float x) {
    unsigned u = __float_as_uint(x);
    return (unsigned short)((u + 0x7fffu + ((u >> 16) & 1u)) >> 16);   // RNE
}
__device__ inline float b2f(unsigned short b) {
    return __uint_as_float(((unsigned)b) << 16);
}

#define GLDS(gp, lp) __builtin_amdgcn_global_load_lds( \
    (const __attribute__((address_space(1))) void*)(gp), \
    (__attribute__((address_space(3))) void*)(lp), 16, 0, 0)

// ---------------------------------------------------------------------------
// r19 = r18 kernels + makespan compaction:
//   - gemm_dual: Wcomb (72 blocks, 256x128 instance) + xz (768 blocks) in ONE
//     launch; Wcomb's ~40us (prev. serial at 0.56 blocks/CU) hides under xz.
//   - transpose_all / convert_all: fold 6 tiny preprocessing launches into 2.
// GEMM inner structure unchanged (proven r14/r15 family; plateau r13-r18).
// ---------------------------------------------------------------------------

// 256x128 (MxN), 8 waves, parameterized (wg,nwg) so multiple sub-grids can
// share one launch.  NT=K/32 even.  EPI: 0 plain (OUTBF16 sel),
// 3 fused xp+delta (gn<32 -> f32 C2, else softplus(acc+bias[gn-32]) -> bf16).
template<int EPI, int OUTBF16>
__device__ __forceinline__ void gemm_w8_body(
    int wg, int nwg,
    unsigned short (&As0)[256*32], unsigned short (&As1)[256*32],
    unsigned short (&Bs0)[128*32], unsigned short (&Bs1)[128*32],
    const unsigned short* __restrict__ A, int lda,
    const unsigned short* __restrict__ Bt, int ldb,
    void* __restrict__ Cv, int ldc, float* __restrict__ C2,
    int N, int K, const float* __restrict__ bias, int nbx)
{
    const int cpx = nwg >> 3;
    const int xcd = wg & 7, local = wg >> 3;
    int bmi, bni;
    if ((cpx % nbx == 0) && ((nbx & 1) == 0)) {
        const int R   = cpx / nbx;
        const int p   = local / (2 * R);
        const int idx = local % (2 * R);
        bmi = xcd * R + (idx >> 1);
        bni = p * 2 + (idx & 1);
    } else {
        const int swz = xcd * cpx + local;
        bmi = swz / nbx;
        bni = swz % nbx;
    }
    const int bm = bmi * 256;
    const int bn = bni * 128;

    const int tid  = threadIdx.x;          // 0..511
    const int lane = tid & 63;
    const int wave = tid >> 6;             // 0..7
    const int wm   = (wave >> 1) * 64;     // 0,64,128,192
    const int wn   = (wave & 1) * 64;      // 0,64
    const int l15  = lane & 15;
    const int lg   = lane >> 4;

    const int sr    = tid >> 2;                              // 0..127
    const int sg    = ((tid & 3) ^ ((tid >> 3) & 3)) * 8;    // swizzled src granule
    const int lbase = (tid & ~63) * 16;                      // wave-uniform LDS base

    const unsigned short* pa0 = A  + (size_t)(bm + sr) * lda + sg;
    const unsigned short* pa1 = A  + (size_t)(bm + 128 + sr) * lda + sg;
    const unsigned short* pb0 = Bt + (size_t)(bn + sr) * ldb + sg;

    int aoff[4], boff[4];
    #pragma unroll
    for (int i = 0; i < 4; ++i) {
        const int tr = wm + i * 16 + l15;
        aoff[i] = tr * 64 + ((lg ^ ((tr >> 1) & 3)) << 4);
    }
    #pragma unroll
    for (int j = 0; j < 4; ++j) {
        const int tr = wn + j * 16 + l15;
        boff[j] = tr * 64 + ((lg ^ ((tr >> 1) & 3)) << 4);
    }

    floatx4 acc[4][4] = {};

    auto stage = [&]() {
        // buffer selected by caller via pointer parity — handled by STEP macro
    };
    (void)stage;

    auto stageTo = [&](unsigned short (&SA)[256*32], unsigned short (&SB)[128*32]) {
        GLDS(pa0, (char*)SA + lbase);
        GLDS(pa1, (char*)SA + 8192 + lbase);
        GLDS(pb0, (char*)SB + lbase);
        pa0 += 32; pa1 += 32; pb0 += 32;
    };

    auto compute = [&](const unsigned short (&CA)[256*32],
                       const unsigned short (&CB)[128*32]) {
        short8 af[4], bfv[4];
        #pragma unroll
        for (int i = 0; i < 4; ++i)
            af[i] = *(const short8*)((const char*)&CA[0] + aoff[i]);
        #pragma unroll
        for (int j = 0; j < 4; ++j)
            bfv[j] = *(const short8*)((const char*)&CB[0] + boff[j]);
        #pragma unroll
        for (int i = 0; i < 4; ++i)
            #pragma unroll
            for (int j = 0; j < 4; ++j)
                acc[i][j] = __builtin_amdgcn_mfma_f32_16x16x32_bf16(
                    af[i], bfv[j], acc[i][j], 0, 0, 0);
    };

    const int NT = K >> 5;                 // K/32, even

    stageTo(As0, Bs0);                     // prologue: tile 0 -> buf0

    #define STEP_W8(SA, SB, CA, CB, T)                                       \
    {                                                                        \
        if ((T) + 1 < NT) {                                                  \
            stageTo(SA, SB);                                                 \
            asm volatile("s_waitcnt vmcnt(3)" ::: "memory");                 \
        } else {                                                             \
            asm volatile("s_waitcnt vmcnt(0)" ::: "memory");                 \
        }                                                                    \
        __builtin_amdgcn_sched_barrier(0);                                   \
        __builtin_amdgcn_s_barrier();                                        \
        __builtin_amdgcn_sched_barrier(0);                                   \
        compute(CA, CB);                                                     \
        __builtin_amdgcn_sched_barrier(0);                                   \
        __builtin_amdgcn_s_barrier();                                        \
        __builtin_amdgcn_sched_barrier(0);                                   \
    }

    for (int t = 0; t < NT; t += 2) {
        STEP_W8(As1, Bs1, As0, Bs0, t);
        STEP_W8(As0, Bs0, As1, Bs1, t + 1);
    }
    #undef STEP_W8

    // C/D layout: col = lane&15, row = (lane>>4)*4 + reg  (m89-verified)
    #pragma unroll
    for (int i = 0; i < 4; ++i) {
        #pragma unroll
        for (int r = 0; r < 4; ++r) {
            const int gm = bm + wm + i * 16 + lg * 4 + r;
            #pragma unroll
            for (int j = 0; j < 4; ++j) {
                const int gn = bn + wn + j * 16 + l15;
                float v = acc[i][j][r];
                if (EPI == 3) {
                    if (gn < 32) {
                        C2[(size_t)gm * 32 + gn] = v;
                    } else if (gn < N) {
                        v += bias[gn - 32];
                        v = (v > 20.f) ? v : log1pf(__expf(v));
                        ((unsigned short*)Cv)[(size_t)gm * 1536 + gn - 32] = f2b(v);
                    }
                } else {
                    if (gn < N) {
                        if (OUTBF16)
                            ((unsigned short*)Cv)[(size_t)gm * ldc + gn] = f2b(v);
                        else
                            ((float*)Cv)[(size_t)gm * ldc + gn] = v;
                    }
                }
            }
        }
    }
}

template<int EPI, int OUTBF16>
__global__ __launch_bounds__(512, 4) void gemm_w8(
    const unsigned short* __restrict__ A, int lda,
    const unsigned short* __restrict__ Bt, int ldb,
    void* __restrict__ Cv, int ldc, float* __restrict__ C2,
    int N, int K, const float* __restrict__ bias, int nbx)
{
    __shared__ unsigned short As0[256*32], As1[256*32];
    __shared__ unsigned short Bs0[128*32], Bs1[128*32];
    gemm_w8_body<EPI, OUTBF16>(blockIdx.x, gridDim.x, As0, As1, Bs0, Bs1,
                               A, lda, Bt, ldb, Cv, ldc, C2, N, K, bias, nbx);
}

// Dual launch: blocks 0..71 = Wcomb (256x128 tiles over M=N=1536, K=1536,
// dispatched FIRST since 2x per-block work); blocks 72..839 = xz (K=768).
// Both sub-ranges start at offsets %8==0 so wg&7 == physical XCD round-robin.
__global__ __launch_bounds__(512, 4) void gemm_dual(
    const unsigned short* __restrict__ Wt_dt, const unsigned short* __restrict__ wxb,
    unsigned short* __restrict__ wtx32,
    const unsigned short* __restrict__ hsb, const unsigned short* __restrict__ Wt_in,
    unsigned short* __restrict__ xzb)
{
    __shared__ unsigned short As0[256*32], As1[256*32];
    __shared__ unsigned short Bs0[128*32], Bs1[128*32];
    if (blockIdx.x < 72) {
        gemm_w8_body<0, 1>(blockIdx.x, 72, As0, As1, Bs0, Bs1,
                           Wt_dt, 1536, wxb, 1536, wtx32, 1536, nullptr,
                           1536, 1536, nullptr, 12);
    } else {
        gemm_w8_body<0, 1>(blockIdx.x - 72, 768, As0, As1, Bs0, Bs1,
                           hsb, 768, Wt_in, 768, xzb, 3072, nullptr,
                           3072, 768, nullptr, 24);
    }
}

// 128x128, 4 waves — out-proj (384 blocks).
template<int EPI, int OUTBF16>
__global__ __launch_bounds__(256, 4) void gemm_p2(
    const unsigned short* __restrict__ A, int lda,
    const unsigned short* __restrict__ Bt, int ldb,
    void* __restrict__ Cv, int ldc, float* __restrict__ C2,
    int N, int K, const float* __restrict__ bias, int nbx)
{
    __shared__ unsigned short As0[128*32], As1[128*32];
    __shared__ unsigned short Bs0[128*32], Bs1[128*32];

    const int nwg = gridDim.x;
    const int cpx = nwg >> 3;
    const int wg  = blockIdx.x;
    const int xcd = wg & 7, local = wg >> 3;
    int bmi, bni;
    if ((cpx % nbx == 0) && ((nbx & 1) == 0)) {
        const int R   = cpx / nbx;
        const int p   = local / (2 * R);
        const int idx = local % (2 * R);
        bmi = xcd * R + (idx >> 1);
        bni = p * 2 + (idx & 1);
    } else {
        const int swz = xcd * cpx + local;
        bmi = swz / nbx;
        bni = swz % nbx;
    }
    const int bm = bmi * 128;
    const int bn = bni * 128;

    const int tid  = threadIdx.x;
    const int lane = tid & 63;
    const int wave = tid >> 6;
    const int wm   = (wave >> 1) * 64;
    const int wn   = (wave & 1) * 64;
    const int l15  = lane & 15;
    const int lg   = lane >> 4;

    const int sr    = tid >> 2;
    const int sg    = ((tid & 3) ^ ((tid >> 3) & 3)) * 8;
    const int lbase = (tid & ~63) * 16;

    const unsigned short* pa0 = A  + (size_t)(bm + sr) * lda + sg;
    const unsigned short* pa1 = A  + (size_t)(bm + 64 + sr) * lda + sg;
    const unsigned short* pb0 = Bt + (size_t)(bn + sr) * ldb + sg;
    const unsigned short* pb1 = Bt + (size_t)(bn + 64 + sr) * ldb + sg;

    int aoff[4], boff[4];
    #pragma unroll
    for (int i = 0; i < 4; ++i) {
        const int tr = wm + i * 16 + l15;
        aoff[i] = tr * 64 + ((lg ^ ((tr >> 1) & 3)) << 4);
    }
    #pragma unroll
    for (int j = 0; j < 4; ++j) {
        const int tr = wn + j * 16 + l15;
        boff[j] = tr * 64 + ((lg ^ ((tr >> 1) & 3)) << 4);
    }

    floatx4 acc[4][4] = {};

    auto stage = [&](unsigned short (&SA)[128*32], unsigned short (&SB)[128*32]) {
        GLDS(pa0, (char*)SA + lbase);
        GLDS(pa1, (char*)SA + 4096 + lbase);
        GLDS(pb0, (char*)SB + lbase);
        GLDS(pb1, (char*)SB + 4096 + lbase);
        pa0 += 32; pa1 += 32; pb0 += 32; pb1 += 32;
    };

    auto compute = [&](const unsigned short (&CA)[128*32],
                       const unsigned short (&CB)[128*32]) {
        short8 af[4], bfv[4];
        #pragma unroll
        for (int i = 0; i < 4; ++i)
            af[i] = *(const short8*)((const char*)&CA[0] + aoff[i]);
        #pragma unroll
        for (int j = 0; j < 4; ++j)
            bfv[j] = *(const short8*)((const char*)&CB[0] + boff[j]);
        #pragma unroll
        for (int i = 0; i < 4; ++i)
            #pragma unroll
            for (int j = 0; j < 4; ++j)
                acc[i][j] = __builtin_amdgcn_mfma_f32_16x16x32_bf16(
                    af[i], bfv[j], acc[i][j], 0, 0, 0);
    };

    const int NT = K >> 5;                 // K/32, even

    stage(As0, Bs0);

    #define STEP(SA, SB, CA, CB, T)                                          \
    {                                                                        \
        if ((T) + 1 < NT) {                                                  \
            stage(SA, SB);                                                   \
            asm volatile("s_waitcnt vmcnt(4)" ::: "memory");                 \
        } else {                                                             \
            asm volatile("s_waitcnt vmcnt(0)" ::: "memory");                 \
        }                                                                    \
        __builtin_amdgcn_sched_barrier(0);                                   \
        __builtin_amdgcn_s_barrier();                                        \
        __builtin_amdgcn_sched_barrier(0);                                   \
        compute(CA, CB);                                                     \
        __builtin_amdgcn_sched_barrier(0);                                   \
        __builtin_amdgcn_s_barrier();                                        \
        __builtin_amdgcn_sched_barrier(0);                                   \
    }

    for (int t = 0; t < NT; t += 2) {
        STEP(As1, Bs1, As0, Bs0, t);
        STEP(As0, Bs0, As1, Bs1, t + 1);
    }
    #undef STEP

    #pragma unroll
    for (int i = 0; i < 4; ++i) {
        #pragma unroll
        for (int r = 0; r < 4; ++r) {
            const int gm = bm + wm + i * 16 + lg * 4 + r;
            #pragma unroll
            for (int j = 0; j < 4; ++j) {
                const int gn = bn + wn + j * 16 + l15;
                float v = acc[i][j][r];
                if (gn < N) {
                    if (OUTBF16)
                        ((unsigned short*)Cv)[(size_t)gm * ldc + gn] = f2b(v);
                    else
                        ((float*)Cv)[(size_t)gm * ldc + gn] = v;
                }
            }
        }
    }
}

// ---------------------------------------------------------------------------
// All 4 weight transposes in one launch.  W[K][N] f32 -> Wt[Npad][K] bf16.
// Sub-grids: W_in 96x24=2304 | W_x 56x48=2688 | W_dt 48x48=2304 | W_out 24x48.
// ---------------------------------------------------------------------------
__global__ __launch_bounds__(256) void transpose_all(
    const float* __restrict__ W_in,  unsigned short* __restrict__ Wt_in,
    const float* __restrict__ W_x,   unsigned short* __restrict__ Wt_x,
    const float* __restrict__ W_dt,  unsigned short* __restrict__ Wt_dt,
    const float* __restrict__ W_out, unsigned short* __restrict__ Wt_out)
{
    const int b = blockIdx.x;
    const float* W; unsigned short* Wt; int K, N, nbx, lb;
    if (b < 2304)      { W = W_in;  Wt = Wt_in;  K = 768;  N = 3072; nbx = 96; lb = b; }
    else if (b < 4992) { W = W_x;   Wt = Wt_x;   K = 1536; N = 1568; nbx = 56; lb = b - 2304; }
    else if (b < 7296) { W = W_dt;  Wt = Wt_dt;  K = 1536; N = 1536; nbx = 48; lb = b - 4992; }
    else               { W = W_out; Wt = Wt_out; K = 1536; N = 768;  nbx = 24; lb = b - 7296; }
    const int nt = (lb % nbx) * 32, kt = (lb / nbx) * 32;

    __shared__ float t[32][33];
    const int tx = threadIdx.x & 31, ty = threadIdx.x >> 5;
    #pragma unroll
    for (int r = 0; r < 4; ++r) {
        const int k = ty + r * 8;
        const int n = nt + tx;
        float v = 0.f;
        if (n < N) v = W[(size_t)(kt + k) * N + n];
        t[k][tx] = v;
    }
    __syncthreads();
    #pragma unroll
    for (int r = 0; r < 4; ++r) {
        const int nl = ty + r * 8;
        Wt[(size_t)(nt + nl) * K + kt + tx] = f2b(t[tx][nl]);
    }
}

// hs f32 -> hsb bf16 (NROWS*768) and W_x[:,32:] f32 -> wxb[1536][1536] bf16,
// one launch.  Grid = (NROWS*768/4 + 1536*384) / 256 = 8448.
__global__ __launch_bounds__(256) void convert_all(
    const float* __restrict__ hs, unsigned short* __restrict__ hsb,
    const float* __restrict__ Wx, unsigned short* __restrict__ wxb)
{
    const int NH = NROWS * 768 / 4;
    int i = blockIdx.x * 256 + threadIdx.x;
    if (i < NH) {
        float4 v = ((const float4*)hs)[i];
        ushort4 r;
        r.x = f2b(v.x); r.y = f2b(v.y); r.z = f2b(v.z); r.w = f2b(v.w);
        ((ushort4*)hsb)[i] = r;
    } else {
        i -= NH;
        if (i < 1536 * 384) {
            const int row = i / 384, q = i % 384;
            float4 v = *(const float4*)(Wx + (size_t)row * 1568 + 32 + q * 4);
            ushort4 r;
            r.x = f2b(v.x); r.y = f2b(v.y); r.z = f2b(v.z); r.w = f2b(v.w);
            *(ushort4*)(wxb + (size_t)row * 1536 + q * 4) = r;
        }
    }
}

// ---------------------------------------------------------------------------
// Depthwise causal conv (width 4) + bias + SiLU — 4 rows x 8 channels per
// thread, sliding window.
// ---------------------------------------------------------------------------
__global__ __launch_bounds__(256) void conv_silu4r(
    const unsigned short* __restrict__ xzb, const float* __restrict__ w,
    const float* __restrict__ cb, unsigned short* __restrict__ ub)
{
    const int i = blockIdx.x * 256 + threadIdx.x;    // over (NROWS/4)*192
    if (i >= (NROWS / 4) * 192) return;
    const int g    = i % 192;
    const int rowq = i / 192;
    const int row0 = rowq * 4;
    const int lb   = row0 % SEQLEN;
    const int d0   = g * 8;

    float4 we[8];
    float  cbv[8];
    #pragma unroll
    for (int e = 0; e < 8; ++e) {
        we[e]  = *(const float4*)&w[(d0 + e) * 4];
        cbv[e] = cb[d0 + e];
    }

    short8 xr[7];
    #pragma unroll
    for (int k = 0; k < 7; ++k) {
        const int ll = lb - 3 + k;
        if (ll >= 0)
            xr[k] = *(const short8*)&xzb[(size_t)(row0 - 3 + k) * 3072 + d0];
        else
            xr[k] = short8{0,0,0,0,0,0,0,0};
    }

    #pragma unroll
    for (int r = 0; r < 4; ++r) {
        unsigned short o[8];
        #pragma unroll
        for (int e = 0; e < 8; ++e) {
            float a = cbv[e];
            a = fmaf(b2f((unsigned short)xr[r + 0][e]), we[e].x, a);
            a = fmaf(b2f((unsigned short)xr[r + 1][e]), we[e].y, a);
            a = fmaf(b2f((unsigned short)xr[r + 2][e]), we[e].z, a);
            a = fmaf(b2f((unsigned short)xr[r + 3][e]), we[e].w, a);
            o[e] = f2b(a / (1.f + __expf(-a)));
        }
        *(short8*)&ub[(size_t)(row0 + r) * 1536 + d0] = *(short8*)o;
    }
}

// ---------------------------------------------------------------------------
// Per-row softmax over B (16) + copy C (16) from compact xp32[row][32].
// ---------------------------------------------------------------------------
__global__ __launch_bounds__(256) void softmax_bc_kernel(
    const float* __restrict__ xp32, float* __restrict__ Bsm, float* __restrict__ Csm)
{
    const int row = blockIdx.x * 256 + threadIdx.x;
    if (row >= NROWS) return;
    const float* p = xp32 + (size_t)row * 32;
    float v[16];
    #pragma unroll
    for (int q = 0; q < 4; ++q) {
        float4 t = *(const float4*)(p + q * 4);
        v[q*4+0]=t.x; v[q*4+1]=t.y; v[q*4+2]=t.z; v[q*4+3]=t.w;
    }
    float mx = v[0];
    #pragma unroll
    for (int s = 1; s < 16; ++s) mx = fmaxf(mx, v[s]);
    float sum = 0.f;
    #pragma unroll
    for (int s = 0; s < 16; ++s) { v[s] = __expf(v[s] - mx); sum += v[s]; }
    const float inv = 1.f / sum;
    float* bo = Bsm + (size_t)row * 16;
    float* co = Csm + (size_t)row * 16;
    #pragma unroll
    for (int s = 0; s < 16; ++s) bo[s] = v[s] * inv;
    #pragma unroll
    for (int q = 0; q < 4; ++q)
        *(float4*)(co + q * 4) = *(const float4*)(p + 16 + q * 4);
}

// ---------------------------------------------------------------------------
// Scan phase A: per (b, chunk, d): chunk-final state (zero init) + dt-sum.
// ---------------------------------------------------------------------------
__global__ __launch_bounds__(256) void scan_chunk_state(
    const unsigned short* __restrict__ deltab, const unsigned short* __restrict__ ub,
    const float* __restrict__ Bsm, const float* __restrict__ A_log,
    float* __restrict__ chunkS, float* __restrict__ dtsum)
{
    const int gid = blockIdx.x * 256 + threadIdx.x;   // (b*NCHUNK+c)*D_INNER+d
    const int d = gid % D_INNER;
    const int c = (gid / D_INNER) % NCHUNK;
    const int b = gid / (D_INNER * NCHUNK);

    float A2[16];
    #pragma unroll
    for (int q = 0; q < 4; ++q) {
        float4 t = *(const float4*)(A_log + d * 16 + q * 4);
        A2[q*4+0] = -__expf(t.x) * 1.44269504089f;
        A2[q*4+1] = -__expf(t.y) * 1.44269504089f;
        A2[q*4+2] = -__expf(t.z) * 1.44269504089f;
        A2[q*4+3] = -__expf(t.w) * 1.44269504089f;
    }
    float h[16];
    #pragma unroll
    for (int s = 0; s < 16; ++s) h[s] = 0.f;
    float dts = 0.f;

    const int t0 = c * LCHUNK;
    for (int t = t0; t < t0 + LCHUNK; ++t) {
        const size_t rowoff = (size_t)b * SEQLEN + t;
        const float dt = b2f(deltab[rowoff * D_INNER + d]);
        const float uu = b2f(ub[rowoff * D_INNER + d]);
        const float du = dt * uu;
        dts += dt;
        const float4* Bp = (const float4*)(Bsm + rowoff * 16);
        float Bv[16];
        #pragma unroll
        for (int q = 0; q < 4; ++q) {
            float4 tb = Bp[q];
            Bv[q*4+0]=tb.x; Bv[q*4+1]=tb.y; Bv[q*4+2]=tb.z; Bv[q*4+3]=tb.w;
        }
        #pragma unroll
        for (int s = 0; s < 16; ++s) {
            const float dA = exp2f(dt * A2[s]);
            h[s] = fmaf(dA, h[s], du * Bv[s]);
        }
    }
    float* S = chunkS + (size_t)gid * 16;
    #pragma unroll
    for (int q = 0; q < 4; ++q)
        *(float4*)(S + q * 4) = make_float4(h[q*4+0], h[q*4+1], h[q*4+2], h[q*4+3]);
    dtsum[gid] = dts;
}

// ---------------------------------------------------------------------------
// Scan phase B: inter-chunk scan; chunkS becomes chunk-INITIAL states.
// ---------------------------------------------------------------------------
__global__ __launch_bounds__(256) void scan_chunk_scan(
    const float* __restrict__ A_log, const float* __restrict__ dtsum,
    float* __restrict__ chunkS)
{
    const int gid = blockIdx.x * 256 + threadIdx.x;   // (b*D_INNER+d)*16+s
    if (gid >= BATCH * D_INNER * 16) return;
    const int s = gid % 16;
    const int d = (gid / 16) % D_INNER;
    const int b = gid / (16 * D_INNER);
    const float A2 = -__expf(A_log[d * 16 + s]) * 1.44269504089f;
    float hprev = 0.f;
    for (int c = 0; c < NCHUNK; ++c) {
        const size_t cidx = ((size_t)(b * NCHUNK + c) * D_INNER + d);
        const float P  = exp2f(A2 * dtsum[cidx]);
        const size_t idx = cidx * 16 + s;
        const float Sc = chunkS[idx];
        chunkS[idx] = hprev;
        hprev = fmaf(P, hprev, Sc);
    }
}

// ---------------------------------------------------------------------------
// Scan phase C: re-run chunks from initial states, y = (C.h) * silu(z), bf16.
// ---------------------------------------------------------------------------
__global__ __launch_bounds__(256) void scan_output(
    const unsigned short* __restrict__ deltab, const unsigned short* __restrict__ ub,
    const float* __restrict__ Bsm, const float* __restrict__ Csm,
    const float* __restrict__ A_log, const float* __restrict__ chunkS,
    const unsigned short* __restrict__ xzb, unsigned short* __restrict__ yb)
{
    const int gid = blockIdx.x * 256 + threadIdx.x;
    const int d = gid % D_INNER;
    const int c = (gid / D_INNER) % NCHUNK;
    const int b = gid / (D_INNER * NCHUNK);

    float A2[16];
    #pragma unroll
    for (int q = 0; q < 4; ++q) {
        float4 t = *(const float4*)(A_log + d * 16 + q * 4);
        A2[q*4+0] = -__expf(t.x) * 1.44269504089f;
        A2[q*4+1] = -__expf(t.y) * 1.44269504089f;
        A2[q*4+2] = -__expf(t.z) * 1.44269504089f;
        A2[q*4+3] = -__expf(t.w) * 1.44269504089f;
    }
    float h[16];
    const float* S = chunkS + (size_t)gid * 16;
    #pragma unroll
    for (int q = 0; q < 4; ++q) {
        float4 t = *(const float4*)(S + q * 4);
        h[q*4+0]=t.x; h[q*4+1]=t.y; h[q*4+2]=t.z; h[q*4+3]=t.w;
    }

    const int t0 = c * LCHUNK;
    for (int t = t0; t < t0 + LCHUNK; ++t) {
        const size_t rowoff = (size_t)b * SEQLEN + t;
        const float dt = b2f(deltab[rowoff * D_INNER + d]);
        const float uu = b2f(ub[rowoff * D_INNER + d]);
        const float du = dt * uu;
        const float4* Bp = (const float4*)(Bsm + rowoff * 16);
        const float4* Cp = (const float4*)(Csm + rowoff * 16);
        float Bv[16], Cv[16];
        #pragma unroll
        for (int q = 0; q < 4; ++q) {
            float4 tb = Bp[q], tc = Cp[q];
            Bv[q*4+0]=tb.x; Bv[q*4+1]=tb.y; Bv[q*4+2]=tb.z; Bv[q*4+3]=tb.w;
            Cv[q*4+0]=tc.x; Cv[q*4+1]=tc.y; Cv[q*4+2]=tc.z; Cv[q*4+3]=tc.w;
        }
        float yv = 0.f;
        #pragma unroll
        for (int s = 0; s < 16; ++s) {
            const float dA = exp2f(dt * A2[s]);
            h[s] = fmaf(dA, h[s], du * Bv[s]);
            yv = fmaf(Cv[s], h[s], yv);
        }
        const float z = b2f(xzb[rowoff * (2 * D_INNER) + D_INNER + d]);
        const float sz = z / (1.f + __expf(-z));
        yb[rowoff * D_INNER + d] = f2b(yv * sz);
    }
}

// ---------------------------------------------------------------------------
extern "C" void kernel_launch(void* const* d_in, const int* in_sizes, int n_in,
                              void* d_out, int out_size, void* d_ws, size_t ws_size,
                              hipStream_t stream)
{
    const float* hs     = (const float*)d_in[0];
    const float* W_in   = (const float*)d_in[1];
    const float* conv_w = (const float*)d_in[2];
    const float* conv_b = (const float*)d_in[3];
    const float* W_x    = (const float*)d_in[4];
    const float* W_dt   = (const float*)d_in[5];
    const float* b_dt   = (const float*)d_in[6];
    const float* A_log  = (const float*)d_in[7];
    const float* W_out  = (const float*)d_in[9];
    float* out = (float*)d_out;

    // workspace layout (256B aligned)
    char* w = (char*)d_ws;
    auto alloc = [&](size_t bytes) { char* p = w; w += (bytes + 255) & ~(size_t)255; return p; };
    float*          xp32   = (float*)alloc((size_t)NROWS * 32 * 4);
    unsigned short* deltab = (unsigned short*)alloc((size_t)NROWS * 1536 * 2);
    float*          Bsm    = (float*)alloc((size_t)NROWS * 16 * 4);
    float*          Csm    = (float*)alloc((size_t)NROWS * 16 * 4);
    float*          chunkS = (float*)alloc((size_t)BATCH * NCHUNK * D_INNER * 16 * 4);
    float*          dtsum  = (float*)alloc((size_t)BATCH * NCHUNK * D_INNER * 4);
    unsigned short* xzb    = (unsigned short*)alloc((size_t)NROWS * 3072 * 2);
    unsigned short* ub     = (unsigned short*)alloc((size_t)NROWS * 1536 * 2);
    unsigned short* yb     = (unsigned short*)alloc((size_t)NROWS * 1536 * 2);
    unsigned short* hsb    = (unsigned short*)alloc((size_t)NROWS * 768 * 2);
    unsigned short* Wt_in  = (unsigned short*)alloc((size_t)3072 * 768 * 2);
    unsigned short* Wt_x   = (unsigned short*)alloc((size_t)1792 * 1536 * 2);
    unsigned short* Wt_dt  = (unsigned short*)alloc((size_t)1536 * 1536 * 2);
    unsigned short* Wt_out = (unsigned short*)alloc((size_t)768 * 1536 * 2);
    unsigned short* wxb    = (unsigned short*)alloc((size_t)1536 * 1536 * 2);

    const dim3 blk(256);

    // 0) all weight transposes (1 launch) + all converts (1 launch)
    transpose_all<<<dim3(8448), blk, 0, stream>>>(
        W_in, Wt_in, W_x, Wt_x, W_dt, Wt_dt, W_out, Wt_out);
    convert_all<<<dim3(8448), blk, 0, stream>>>(hs, hsb, W_x, wxb);

    // 1) DUAL: Wcomb^T -> Wt_x rows 32.. (72 blocks, first) + xz GEMM (768)
    gemm_dual<<<dim3(840), dim3(512), 0, stream>>>(
        Wt_dt, wxb, Wt_x + (size_t)32 * 1536, hsb, Wt_in, xzb);

    // 2) u = silu(conv(x) + cb)  [4 rows/thread sliding window]
    conv_silu4r<<<((NROWS/4)*192)/256, blk, 0, stream>>>(xzb, conv_w, conv_b, ub);

    // 3) fused xp+delta GEMM: u @ [W_x[:,:32] | W_comb]
    //    [256x128 8-wave; K=1536; grid 32*13=416, %8==0]
    gemm_w8<3,0><<<dim3(416), dim3(512), 0, stream>>>(
        ub, 1536, Wt_x, 1536, deltab, 1536, xp32, 1568, 1536, b_dt, 13);

    // 4) Bsm = softmax(xp32[:, :16]), Csm = xp32[:, 16:32]
    softmax_bc_kernel<<<NROWS/256, blk, 0, stream>>>(xp32, Bsm, Csm);

    // 5-7) chunked selective scan (NCHUNK=128: 1536 blocks for A/C)
    scan_chunk_state<<<(BATCH*NCHUNK*D_INNER)/256, blk, 0, stream>>>(
        deltab, ub, Bsm, A_log, chunkS, dtsum);
    scan_chunk_scan<<<(BATCH*D_INNER*16 + 255)/256, blk, 0, stream>>>(
        A_log, dtsum, chunkS);
    scan_output<<<(BATCH*NCHUNK*D_INNER)/256, blk, 0, stream>>>(
        deltab, ub, Bsm, Csm, A_log, chunkS, xzb, yb);

    // 8) out = y @ W_out  (f32 out)  [128^2; grid 6*64=384, %8==0]
    gemm_p2<0,0><<<dim3(384), blk, 0, stream>>>(
        yb, 1536, Wt_out, 1536, out, 768, nullptr, 768, 1536, nullptr, 6);
}

// Round 20
// 392.536 us; speedup vs baseline: 1.3560x; 1.0414x over previous
//
#include <hip/hip_runtime.h>
#include <hip/hip_bf16.h>
#include <math.h>

#define D_MODEL 768
#define D_STATE 16
#define D_CONVW 4
#define D_INNER 1536
#define BATCH   2
#define SEQLEN  4096
#define NROWS   (BATCH*SEQLEN)       // 8192
#define NCHUNK  128                  // scan TLP: 1536 blocks for phases A/C
#define LCHUNK  (SEQLEN/NCHUNK)      // 32

typedef __attribute__((ext_vector_type(8))) short short8;
typedef __attribute__((ext_vector_type(4))) float floatx4;

__device__ inline unsigned short f2b(float x) {
    unsigned u = __float_as_uint(x);
    return (unsigned short)((u + 0x7fffu + ((u >> 16) & 1u)) >> 16);   // RNE
}
__device__ inline float b2f(unsigned short b) {
    return __uint_as_float(((unsigned)b) << 16);
}

#define GLDS(gp, lp) __builtin_amdgcn_global_load_lds( \
    (const __attribute__((address_space(1))) void*)(gp), \
    (__attribute__((address_space(3))) void*)(lp), 16, 0, 0)

// ---------------------------------------------------------------------------
// r20 = r19 + (1) softmax fused into gemm_w8 EPI=3 epilogue (bn==0/wn==0
// waves hold each row's 16 B-cols in one 16-lane group -> 4-step shfl_xor
// softmax, write Bsm/Csm directly; xp32 round-trip + softmax kernel deleted),
// (2) preprocess_all: transposes + converts in ONE launch.
// GEMM inner structure unchanged (plateau r13-r18 established).
// ---------------------------------------------------------------------------

// 256x128 (MxN), 8 waves, parameterized (wg,nwg).  NT=K/32 even.
// EPI: 0 plain (OUTBF16 sel); 3 fused xp+delta+softmax:
//   gn<16 -> Bsm[gm*16+gn] = softmax row; gn 16..31 -> Csm; gn>=32 ->
//   softplus(acc+bias[gn-32]) -> bf16 Cv[gm*1536+gn-32].
template<int EPI, int OUTBF16>
__device__ __forceinline__ void gemm_w8_body(
    int wg, int nwg,
    unsigned short (&As0)[256*32], unsigned short (&As1)[256*32],
    unsigned short (&Bs0)[128*32], unsigned short (&Bs1)[128*32],
    const unsigned short* __restrict__ A, int lda,
    const unsigned short* __restrict__ Bt, int ldb,
    void* __restrict__ Cv, int ldc,
    float* __restrict__ Bsm_, float* __restrict__ Csm_,
    int N, int K, const float* __restrict__ bias, int nbx)
{
    const int cpx = nwg >> 3;
    const int xcd = wg & 7, local = wg >> 3;
    int bmi, bni;
    if ((cpx % nbx == 0) && ((nbx & 1) == 0)) {
        const int R   = cpx / nbx;
        const int p   = local / (2 * R);
        const int idx = local % (2 * R);
        bmi = xcd * R + (idx >> 1);
        bni = p * 2 + (idx & 1);
    } else {
        const int swz = xcd * cpx + local;
        bmi = swz / nbx;
        bni = swz % nbx;
    }
    const int bm = bmi * 256;
    const int bn = bni * 128;

    const int tid  = threadIdx.x;          // 0..511
    const int lane = tid & 63;
    const int wave = tid >> 6;             // 0..7
    const int wm   = (wave >> 1) * 64;     // 0,64,128,192
    const int wn   = (wave & 1) * 64;      // 0,64
    const int l15  = lane & 15;
    const int lg   = lane >> 4;

    const int sr    = tid >> 2;                              // 0..127
    const int sg    = ((tid & 3) ^ ((tid >> 3) & 3)) * 8;    // swizzled src granule
    const int lbase = (tid & ~63) * 16;                      // wave-uniform LDS base

    const unsigned short* pa0 = A  + (size_t)(bm + sr) * lda + sg;
    const unsigned short* pa1 = A  + (size_t)(bm + 128 + sr) * lda + sg;
    const unsigned short* pb0 = Bt + (size_t)(bn + sr) * ldb + sg;

    int aoff[4], boff[4];
    #pragma unroll
    for (int i = 0; i < 4; ++i) {
        const int tr = wm + i * 16 + l15;
        aoff[i] = tr * 64 + ((lg ^ ((tr >> 1) & 3)) << 4);
    }
    #pragma unroll
    for (int j = 0; j < 4; ++j) {
        const int tr = wn + j * 16 + l15;
        boff[j] = tr * 64 + ((lg ^ ((tr >> 1) & 3)) << 4);
    }

    floatx4 acc[4][4] = {};

    auto stageTo = [&](unsigned short (&SA)[256*32], unsigned short (&SB)[128*32]) {
        GLDS(pa0, (char*)SA + lbase);
        GLDS(pa1, (char*)SA + 8192 + lbase);
        GLDS(pb0, (char*)SB + lbase);
        pa0 += 32; pa1 += 32; pb0 += 32;
    };

    auto compute = [&](const unsigned short (&CA)[256*32],
                       const unsigned short (&CB)[128*32]) {
        short8 af[4], bfv[4];
        #pragma unroll
        for (int i = 0; i < 4; ++i)
            af[i] = *(const short8*)((const char*)&CA[0] + aoff[i]);
        #pragma unroll
        for (int j = 0; j < 4; ++j)
            bfv[j] = *(const short8*)((const char*)&CB[0] + boff[j]);
        #pragma unroll
        for (int i = 0; i < 4; ++i)
            #pragma unroll
            for (int j = 0; j < 4; ++j)
                acc[i][j] = __builtin_amdgcn_mfma_f32_16x16x32_bf16(
                    af[i], bfv[j], acc[i][j], 0, 0, 0);
    };

    const int NT = K >> 5;                 // K/32, even

    stageTo(As0, Bs0);                     // prologue: tile 0 -> buf0

    #define STEP_W8(SA, SB, CA, CB, T)                                       \
    {                                                                        \
        if ((T) + 1 < NT) {                                                  \
            stageTo(SA, SB);                                                 \
            asm volatile("s_waitcnt vmcnt(3)" ::: "memory");                 \
        } else {                                                             \
            asm volatile("s_waitcnt vmcnt(0)" ::: "memory");                 \
        }                                                                    \
        __builtin_amdgcn_sched_barrier(0);                                   \
        __builtin_amdgcn_s_barrier();                                        \
        __builtin_amdgcn_sched_barrier(0);                                   \
        compute(CA, CB);                                                     \
        __builtin_amdgcn_sched_barrier(0);                                   \
        __builtin_amdgcn_s_barrier();                                        \
        __builtin_amdgcn_sched_barrier(0);                                   \
    }

    for (int t = 0; t < NT; t += 2) {
        STEP_W8(As1, Bs1, As0, Bs0, t);
        STEP_W8(As0, Bs0, As1, Bs1, t + 1);
    }
    #undef STEP_W8

    // C/D layout: col = lane&15, row = (lane>>4)*4 + reg  (m89-verified)
    if (EPI == 3) {
        if (bn == 0 && wn == 0) {
            // This wave holds cols 0..63 of its 64 rows.  j=0 -> B (softmax),
            // j=1 -> C (copy), j=2,3 -> delta.  16 lanes sharing lg hold one
            // row's 16 B values -> shfl_xor reduce (wave-uniform path).
            #pragma unroll
            for (int i = 0; i < 4; ++i) {
                #pragma unroll
                for (int r = 0; r < 4; ++r) {
                    const int gm = bm + wm + i * 16 + lg * 4 + r;
                    float bv = acc[i][0][r];
                    float mx = bv;
                    mx = fmaxf(mx, __shfl_xor(mx, 1));
                    mx = fmaxf(mx, __shfl_xor(mx, 2));
                    mx = fmaxf(mx, __shfl_xor(mx, 4));
                    mx = fmaxf(mx, __shfl_xor(mx, 8));
                    float e = __expf(bv - mx);
                    float s = e;
                    s += __shfl_xor(s, 1);
                    s += __shfl_xor(s, 2);
                    s += __shfl_xor(s, 4);
                    s += __shfl_xor(s, 8);
                    Bsm_[(size_t)gm * 16 + l15] = e / s;
                    Csm_[(size_t)gm * 16 + l15] = acc[i][1][r];
                    #pragma unroll
                    for (int j = 2; j < 4; ++j) {
                        const int gn = j * 16 + l15;          // 32..63
                        float v = acc[i][j][r] + bias[gn - 32];
                        v = (v > 20.f) ? v : log1pf(__expf(v));
                        ((unsigned short*)Cv)[(size_t)gm * 1536 + gn - 32] = f2b(v);
                    }
                }
            }
        } else {
            // gn >= 64 here (bn>0 or wn=64): pure delta path.
            #pragma unroll
            for (int i = 0; i < 4; ++i) {
                #pragma unroll
                for (int r = 0; r < 4; ++r) {
                    const int gm = bm + wm + i * 16 + lg * 4 + r;
                    #pragma unroll
                    for (int j = 0; j < 4; ++j) {
                        const int gn = bn + wn + j * 16 + l15;
                        if (gn < N) {
                            float v = acc[i][j][r] + bias[gn - 32];
                            v = (v > 20.f) ? v : log1pf(__expf(v));
                            ((unsigned short*)Cv)[(size_t)gm * 1536 + gn - 32] = f2b(v);
                        }
                    }
                }
            }
        }
    } else {
        #pragma unroll
        for (int i = 0; i < 4; ++i) {
            #pragma unroll
            for (int r = 0; r < 4; ++r) {
                const int gm = bm + wm + i * 16 + lg * 4 + r;
                #pragma unroll
                for (int j = 0; j < 4; ++j) {
                    const int gn = bn + wn + j * 16 + l15;
                    if (gn < N) {
                        float v = acc[i][j][r];
                        if (OUTBF16)
                            ((unsigned short*)Cv)[(size_t)gm * ldc + gn] = f2b(v);
                        else
                            ((float*)Cv)[(size_t)gm * ldc + gn] = v;
                    }
                }
            }
        }
    }
}

template<int EPI, int OUTBF16>
__global__ __launch_bounds__(512, 4) void gemm_w8(
    const unsigned short* __restrict__ A, int lda,
    const unsigned short* __restrict__ Bt, int ldb,
    void* __restrict__ Cv, int ldc,
    float* __restrict__ Bsm_, float* __restrict__ Csm_,
    int N, int K, const float* __restrict__ bias, int nbx)
{
    __shared__ unsigned short As0[256*32], As1[256*32];
    __shared__ unsigned short Bs0[128*32], Bs1[128*32];
    gemm_w8_body<EPI, OUTBF16>(blockIdx.x, gridDim.x, As0, As1, Bs0, Bs1,
                               A, lda, Bt, ldb, Cv, ldc, Bsm_, Csm_, N, K,
                               bias, nbx);
}

// Dual launch: blocks 0..71 = Wcomb (256x128 tiles, 2x work, dispatched
// first); 72..839 = xz (K=768).  Both offsets %8==0.
__global__ __launch_bounds__(512, 4) void gemm_dual(
    const unsigned short* __restrict__ Wt_dt, const unsigned short* __restrict__ wxb,
    unsigned short* __restrict__ wtx32,
    const unsigned short* __restrict__ hsb, const unsigned short* __restrict__ Wt_in,
    unsigned short* __restrict__ xzb)
{
    __shared__ unsigned short As0[256*32], As1[256*32];
    __shared__ unsigned short Bs0[128*32], Bs1[128*32];
    if (blockIdx.x < 72) {
        gemm_w8_body<0, 1>(blockIdx.x, 72, As0, As1, Bs0, Bs1,
                           Wt_dt, 1536, wxb, 1536, wtx32, 1536, nullptr,
                           nullptr, 1536, 1536, nullptr, 12);
    } else {
        gemm_w8_body<0, 1>(blockIdx.x - 72, 768, As0, As1, Bs0, Bs1,
                           hsb, 768, Wt_in, 768, xzb, 3072, nullptr,
                           nullptr, 3072, 768, nullptr, 24);
    }
}

// 128x128, 4 waves — out-proj (384 blocks).
template<int EPI, int OUTBF16>
__global__ __launch_bounds__(256, 4) void gemm_p2(
    const unsigned short* __restrict__ A, int lda,
    const unsigned short* __restrict__ Bt, int ldb,
    void* __restrict__ Cv, int ldc, int N, int K, int nbx)
{
    __shared__ unsigned short As0[128*32], As1[128*32];
    __shared__ unsigned short Bs0[128*32], Bs1[128*32];

    const int nwg = gridDim.x;
    const int cpx = nwg >> 3;
    const int wg  = blockIdx.x;
    const int xcd = wg & 7, local = wg >> 3;
    int bmi, bni;
    if ((cpx % nbx == 0) && ((nbx & 1) == 0)) {
        const int R   = cpx / nbx;
        const int p   = local / (2 * R);
        const int idx = local % (2 * R);
        bmi = xcd * R + (idx >> 1);
        bni = p * 2 + (idx & 1);
    } else {
        const int swz = xcd * cpx + local;
        bmi = swz / nbx;
        bni = swz % nbx;
    }
    const int bm = bmi * 128;
    const int bn = bni * 128;

    const int tid  = threadIdx.x;
    const int lane = tid & 63;
    const int wave = tid >> 6;
    const int wm   = (wave >> 1) * 64;
    const int wn   = (wave & 1) * 64;
    const int l15  = lane & 15;
    const int lg   = lane >> 4;

    const int sr    = tid >> 2;
    const int sg    = ((tid & 3) ^ ((tid >> 3) & 3)) * 8;
    const int lbase = (tid & ~63) * 16;

    const unsigned short* pa0 = A  + (size_t)(bm + sr) * lda + sg;
    const unsigned short* pa1 = A  + (size_t)(bm + 64 + sr) * lda + sg;
    const unsigned short* pb0 = Bt + (size_t)(bn + sr) * ldb + sg;
    const unsigned short* pb1 = Bt + (size_t)(bn + 64 + sr) * ldb + sg;

    int aoff[4], boff[4];
    #pragma unroll
    for (int i = 0; i < 4; ++i) {
        const int tr = wm + i * 16 + l15;
        aoff[i] = tr * 64 + ((lg ^ ((tr >> 1) & 3)) << 4);
    }
    #pragma unroll
    for (int j = 0; j < 4; ++j) {
        const int tr = wn + j * 16 + l15;
        boff[j] = tr * 64 + ((lg ^ ((tr >> 1) & 3)) << 4);
    }

    floatx4 acc[4][4] = {};

    auto stage = [&](unsigned short (&SA)[128*32], unsigned short (&SB)[128*32]) {
        GLDS(pa0, (char*)SA + lbase);
        GLDS(pa1, (char*)SA + 4096 + lbase);
        GLDS(pb0, (char*)SB + lbase);
        GLDS(pb1, (char*)SB + 4096 + lbase);
        pa0 += 32; pa1 += 32; pb0 += 32; pb1 += 32;
    };

    auto compute = [&](const unsigned short (&CA)[128*32],
                       const unsigned short (&CB)[128*32]) {
        short8 af[4], bfv[4];
        #pragma unroll
        for (int i = 0; i < 4; ++i)
            af[i] = *(const short8*)((const char*)&CA[0] + aoff[i]);
        #pragma unroll
        for (int j = 0; j < 4; ++j)
            bfv[j] = *(const short8*)((const char*)&CB[0] + boff[j]);
        #pragma unroll
        for (int i = 0; i < 4; ++i)
            #pragma unroll
            for (int j = 0; j < 4; ++j)
                acc[i][j] = __builtin_amdgcn_mfma_f32_16x16x32_bf16(
                    af[i], bfv[j], acc[i][j], 0, 0, 0);
    };

    const int NT = K >> 5;                 // K/32, even

    stage(As0, Bs0);

    #define STEP(SA, SB, CA, CB, T)                                          \
    {                                                                        \
        if ((T) + 1 < NT) {                                                  \
            stage(SA, SB);                                                   \
            asm volatile("s_waitcnt vmcnt(4)" ::: "memory");                 \
        } else {                                                             \
            asm volatile("s_waitcnt vmcnt(0)" ::: "memory");                 \
        }                                                                    \
        __builtin_amdgcn_sched_barrier(0);                                   \
        __builtin_amdgcn_s_barrier();                                        \
        __builtin_amdgcn_sched_barrier(0);                                   \
        compute(CA, CB);                                                     \
        __builtin_amdgcn_sched_barrier(0);                                   \
        __builtin_amdgcn_s_barrier();                                        \
        __builtin_amdgcn_sched_barrier(0);                                   \
    }

    for (int t = 0; t < NT; t += 2) {
        STEP(As1, Bs1, As0, Bs0, t);
        STEP(As0, Bs0, As1, Bs1, t + 1);
    }
    #undef STEP

    #pragma unroll
    for (int i = 0; i < 4; ++i) {
        #pragma unroll
        for (int r = 0; r < 4; ++r) {
            const int gm = bm + wm + i * 16 + lg * 4 + r;
            #pragma unroll
            for (int j = 0; j < 4; ++j) {
                const int gn = bn + wn + j * 16 + l15;
                float v = acc[i][j][r];
                if (gn < N) {
                    if (OUTBF16)
                        ((unsigned short*)Cv)[(size_t)gm * ldc + gn] = f2b(v);
                    else
                        ((float*)Cv)[(size_t)gm * ldc + gn] = v;
                }
            }
        }
    }
}

// ---------------------------------------------------------------------------
// ALL preprocessing in one launch: 4 weight transposes (blocks 0..8447) +
// hs->bf16 and W_x[:,32:]->bf16 converts (blocks 8448..16895).
// ---------------------------------------------------------------------------
__global__ __launch_bounds__(256) void preprocess_all(
    const float* __restrict__ W_in,  unsigned short* __restrict__ Wt_in,
    const float* __restrict__ W_x,   unsigned short* __restrict__ Wt_x,
    const float* __restrict__ W_dt,  unsigned short* __restrict__ Wt_dt,
    const float* __restrict__ W_out, unsigned short* __restrict__ Wt_out,
    const float* __restrict__ hs,    unsigned short* __restrict__ hsb,
    unsigned short* __restrict__ wxb)
{
    int b = blockIdx.x;
    if (b < 8448) {
        const float* W; unsigned short* Wt; int K, N, nbx, lb;
        if (b < 2304)      { W = W_in;  Wt = Wt_in;  K = 768;  N = 3072; nbx = 96; lb = b; }
        else if (b < 4992) { W = W_x;   Wt = Wt_x;   K = 1536; N = 1568; nbx = 56; lb = b - 2304; }
        else if (b < 7296) { W = W_dt;  Wt = Wt_dt;  K = 1536; N = 1536; nbx = 48; lb = b - 4992; }
        else               { W = W_out; Wt = Wt_out; K = 1536; N = 768;  nbx = 24; lb = b - 7296; }
        const int nt = (lb % nbx) * 32, kt = (lb / nbx) * 32;

        __shared__ float t[32][33];
        const int tx = threadIdx.x & 31, ty = threadIdx.x >> 5;
        #pragma unroll
        for (int r = 0; r < 4; ++r) {
            const int k = ty + r * 8;
            const int n = nt + tx;
            float v = 0.f;
            if (n < N) v = W[(size_t)(kt + k) * N + n];
            t[k][tx] = v;
        }
        __syncthreads();
        #pragma unroll
        for (int r = 0; r < 4; ++r) {
            const int nl = ty + r * 8;
            Wt[(size_t)(nt + nl) * K + kt + tx] = f2b(t[tx][nl]);
        }
    } else {
        const int NH = NROWS * 768 / 4;
        int i = (b - 8448) * 256 + threadIdx.x;
        if (i < NH) {
            float4 v = ((const float4*)hs)[i];
            ushort4 r;
            r.x = f2b(v.x); r.y = f2b(v.y); r.z = f2b(v.z); r.w = f2b(v.w);
            ((ushort4*)hsb)[i] = r;
        } else {
            i -= NH;
            if (i < 1536 * 384) {
                const int row = i / 384, q = i % 384;
                float4 v = *(const float4*)(W_x + (size_t)row * 1568 + 32 + q * 4);
                ushort4 r;
                r.x = f2b(v.x); r.y = f2b(v.y); r.z = f2b(v.z); r.w = f2b(v.w);
                *(ushort4*)(wxb + (size_t)row * 1536 + q * 4) = r;
            }
        }
    }
}

// ---------------------------------------------------------------------------
// Depthwise causal conv (width 4) + bias + SiLU — 4 rows x 8 channels per
// thread, sliding window.
// ---------------------------------------------------------------------------
__global__ __launch_bounds__(256) void conv_silu4r(
    const unsigned short* __restrict__ xzb, const float* __restrict__ w,
    const float* __restrict__ cb, unsigned short* __restrict__ ub)
{
    const int i = blockIdx.x * 256 + threadIdx.x;    // over (NROWS/4)*192
    if (i >= (NROWS / 4) * 192) return;
    const int g    = i % 192;
    const int rowq = i / 192;
    const int row0 = rowq * 4;
    const int lb   = row0 % SEQLEN;
    const int d0   = g * 8;

    float4 we[8];
    float  cbv[8];
    #pragma unroll
    for (int e = 0; e < 8; ++e) {
        we[e]  = *(const float4*)&w[(d0 + e) * 4];
        cbv[e] = cb[d0 + e];
    }

    short8 xr[7];
    #pragma unroll
    for (int k = 0; k < 7; ++k) {
        const int ll = lb - 3 + k;
        if (ll >= 0)
            xr[k] = *(const short8*)&xzb[(size_t)(row0 - 3 + k) * 3072 + d0];
        else
            xr[k] = short8{0,0,0,0,0,0,0,0};
    }

    #pragma unroll
    for (int r = 0; r < 4; ++r) {
        unsigned short o[8];
        #pragma unroll
        for (int e = 0; e < 8; ++e) {
            float a = cbv[e];
            a = fmaf(b2f((unsigned short)xr[r + 0][e]), we[e].x, a);
            a = fmaf(b2f((unsigned short)xr[r + 1][e]), we[e].y, a);
            a = fmaf(b2f((unsigned short)xr[r + 2][e]), we[e].z, a);
            a = fmaf(b2f((unsigned short)xr[r + 3][e]), we[e].w, a);
            o[e] = f2b(a / (1.f + __expf(-a)));
        }
        *(short8*)&ub[(size_t)(row0 + r) * 1536 + d0] = *(short8*)o;
    }
}

// ---------------------------------------------------------------------------
// Scan phase A: per (b, chunk, d): chunk-final state (zero init) + dt-sum.
// ---------------------------------------------------------------------------
__global__ __launch_bounds__(256) void scan_chunk_state(
    const unsigned short* __restrict__ deltab, const unsigned short* __restrict__ ub,
    const float* __restrict__ Bsm, const float* __restrict__ A_log,
    float* __restrict__ chunkS, float* __restrict__ dtsum)
{
    const int gid = blockIdx.x * 256 + threadIdx.x;   // (b*NCHUNK+c)*D_INNER+d
    const int d = gid % D_INNER;
    const int c = (gid / D_INNER) % NCHUNK;
    const int b = gid / (D_INNER * NCHUNK);

    float A2[16];
    #pragma unroll
    for (int q = 0; q < 4; ++q) {
        float4 t = *(const float4*)(A_log + d * 16 + q * 4);
        A2[q*4+0] = -__expf(t.x) * 1.44269504089f;
        A2[q*4+1] = -__expf(t.y) * 1.44269504089f;
        A2[q*4+2] = -__expf(t.z) * 1.44269504089f;
        A2[q*4+3] = -__expf(t.w) * 1.44269504089f;
    }
    float h[16];
    #pragma unroll
    for (int s = 0; s < 16; ++s) h[s] = 0.f;
    float dts = 0.f;

    const int t0 = c * LCHUNK;
    for (int t = t0; t < t0 + LCHUNK; ++t) {
        const size_t rowoff = (size_t)b * SEQLEN + t;
        const float dt = b2f(deltab[rowoff * D_INNER + d]);
        const float uu = b2f(ub[rowoff * D_INNER + d]);
        const float du = dt * uu;
        dts += dt;
        const float4* Bp = (const float4*)(Bsm + rowoff * 16);
        float Bv[16];
        #pragma unroll
        for (int q = 0; q < 4; ++q) {
            float4 tb = Bp[q];
            Bv[q*4+0]=tb.x; Bv[q*4+1]=tb.y; Bv[q*4+2]=tb.z; Bv[q*4+3]=tb.w;
        }
        #pragma unroll
        for (int s = 0; s < 16; ++s) {
            const float dA = exp2f(dt * A2[s]);
            h[s] = fmaf(dA, h[s], du * Bv[s]);
        }
    }
    float* S = chunkS + (size_t)gid * 16;
    #pragma unroll
    for (int q = 0; q < 4; ++q)
        *(float4*)(S + q * 4) = make_float4(h[q*4+0], h[q*4+1], h[q*4+2], h[q*4+3]);
    dtsum[gid] = dts;
}

// ---------------------------------------------------------------------------
// Scan phase B: inter-chunk scan; chunkS becomes chunk-INITIAL states.
// ---------------------------------------------------------------------------
__global__ __launch_bounds__(256) void scan_chunk_scan(
    const float* __restrict__ A_log, const float* __restrict__ dtsum,
    float* __restrict__ chunkS)
{
    const int gid = blockIdx.x * 256 + threadIdx.x;   // (b*D_INNER+d)*16+s
    if (gid >= BATCH * D_INNER * 16) return;
    const int s = gid % 16;
    const int d = (gid / 16) % D_INNER;
    const int b = gid / (16 * D_INNER);
    const float A2 = -__expf(A_log[d * 16 + s]) * 1.44269504089f;
    float hprev = 0.f;
    for (int c = 0; c < NCHUNK; ++c) {
        const size_t cidx = ((size_t)(b * NCHUNK + c) * D_INNER + d);
        const float P  = exp2f(A2 * dtsum[cidx]);
        const size_t idx = cidx * 16 + s;
        const float Sc = chunkS[idx];
        chunkS[idx] = hprev;
        hprev = fmaf(P, hprev, Sc);
    }
}

// ---------------------------------------------------------------------------
// Scan phase C: re-run chunks from initial states, y = (C.h) * silu(z), bf16.
// ---------------------------------------------------------------------------
__global__ __launch_bounds__(256) void scan_output(
    const unsigned short* __restrict__ deltab, const unsigned short* __restrict__ ub,
    const float* __restrict__ Bsm, const float* __restrict__ Csm,
    const float* __restrict__ A_log, const float* __restrict__ chunkS,
    const unsigned short* __restrict__ xzb, unsigned short* __restrict__ yb)
{
    const int gid = blockIdx.x * 256 + threadIdx.x;
    const int d = gid % D_INNER;
    const int c = (gid / D_INNER) % NCHUNK;
    const int b = gid / (D_INNER * NCHUNK);

    float A2[16];
    #pragma unroll
    for (int q = 0; q < 4; ++q) {
        float4 t = *(const float4*)(A_log + d * 16 + q * 4);
        A2[q*4+0] = -__expf(t.x) * 1.44269504089f;
        A2[q*4+1] = -__expf(t.y) * 1.44269504089f;
        A2[q*4+2] = -__expf(t.z) * 1.44269504089f;
        A2[q*4+3] = -__expf(t.w) * 1.44269504089f;
    }
    float h[16];
    const float* S = chunkS + (size_t)gid * 16;
    #pragma unroll
    for (int q = 0; q < 4; ++q) {
        float4 t = *(const float4*)(S + q * 4);
        h[q*4+0]=t.x; h[q*4+1]=t.y; h[q*4+2]=t.z; h[q*4+3]=t.w;
    }

    const int t0 = c * LCHUNK;
    for (int t = t0; t < t0 + LCHUNK; ++t) {
        const size_t rowoff = (size_t)b * SEQLEN + t;
        const float dt = b2f(deltab[rowoff * D_INNER + d]);
        const float uu = b2f(ub[rowoff * D_INNER + d]);
        const float du = dt * uu;
        const float4* Bp = (const float4*)(Bsm + rowoff * 16);
        const float4* Cp = (const float4*)(Csm + rowoff * 16);
        float Bv[16], Cv[16];
        #pragma unroll
        for (int q = 0; q < 4; ++q) {
            float4 tb = Bp[q], tc = Cp[q];
            Bv[q*4+0]=tb.x; Bv[q*4+1]=tb.y; Bv[q*4+2]=tb.z; Bv[q*4+3]=tb.w;
            Cv[q*4+0]=tc.x; Cv[q*4+1]=tc.y; Cv[q*4+2]=tc.z; Cv[q*4+3]=tc.w;
        }
        float yv = 0.f;
        #pragma unroll
        for (int s = 0; s < 16; ++s) {
            const float dA = exp2f(dt * A2[s]);
            h[s] = fmaf(dA, h[s], du * Bv[s]);
            yv = fmaf(Cv[s], h[s], yv);
        }
        const float z = b2f(xzb[rowoff * (2 * D_INNER) + D_INNER + d]);
        const float sz = z / (1.f + __expf(-z));
        yb[rowoff * D_INNER + d] = f2b(yv * sz);
    }
}

// ---------------------------------------------------------------------------
extern "C" void kernel_launch(void* const* d_in, const int* in_sizes, int n_in,
                              void* d_out, int out_size, void* d_ws, size_t ws_size,
                              hipStream_t stream)
{
    const float* hs     = (const float*)d_in[0];
    const float* W_in   = (const float*)d_in[1];
    const float* conv_w = (const float*)d_in[2];
    const float* conv_b = (const float*)d_in[3];
    const float* W_x    = (const float*)d_in[4];
    const float* W_dt   = (const float*)d_in[5];
    const float* b_dt   = (const float*)d_in[6];
    const float* A_log  = (const float*)d_in[7];
    const float* W_out  = (const float*)d_in[9];
    float* out = (float*)d_out;

    // workspace layout (256B aligned)
    char* w = (char*)d_ws;
    auto alloc = [&](size_t bytes) { char* p = w; w += (bytes + 255) & ~(size_t)255; return p; };
    unsigned short* deltab = (unsigned short*)alloc((size_t)NROWS * 1536 * 2);
    float*          Bsm    = (float*)alloc((size_t)NROWS * 16 * 4);
    float*          Csm    = (float*)alloc((size_t)NROWS * 16 * 4);
    float*          chunkS = (float*)alloc((size_t)BATCH * NCHUNK * D_INNER * 16 * 4);
    float*          dtsum  = (float*)alloc((size_t)BATCH * NCHUNK * D_INNER * 4);
    unsigned short* xzb    = (unsigned short*)alloc((size_t)NROWS * 3072 * 2);
    unsigned short* ub     = (unsigned short*)alloc((size_t)NROWS * 1536 * 2);
    unsigned short* yb     = (unsigned short*)alloc((size_t)NROWS * 1536 * 2);
    unsigned short* hsb    = (unsigned short*)alloc((size_t)NROWS * 768 * 2);
    unsigned short* Wt_in  = (unsigned short*)alloc((size_t)3072 * 768 * 2);
    unsigned short* Wt_x   = (unsigned short*)alloc((size_t)1792 * 1536 * 2);
    unsigned short* Wt_dt  = (unsigned short*)alloc((size_t)1536 * 1536 * 2);
    unsigned short* Wt_out = (unsigned short*)alloc((size_t)768 * 1536 * 2);
    unsigned short* wxb    = (unsigned short*)alloc((size_t)1536 * 1536 * 2);

    const dim3 blk(256);

    // 0) ALL preprocessing in one launch (transposes + converts)
    preprocess_all<<<dim3(16896), blk, 0, stream>>>(
        W_in, Wt_in, W_x, Wt_x, W_dt, Wt_dt, W_out, Wt_out, hs, hsb, wxb);

    // 1) DUAL: Wcomb^T -> Wt_x rows 32.. (72 blocks) + xz GEMM (768 blocks)
    gemm_dual<<<dim3(840), dim3(512), 0, stream>>>(
        Wt_dt, wxb, Wt_x + (size_t)32 * 1536, hsb, Wt_in, xzb);

    // 2) u = silu(conv(x) + cb)  [4 rows/thread sliding window]
    conv_silu4r<<<((NROWS/4)*192)/256, blk, 0, stream>>>(xzb, conv_w, conv_b, ub);

    // 3) fused xp+delta+softmax GEMM: u @ [W_x[:,:32] | W_comb]
    //    cols<16 -> Bsm (in-register softmax), 16..31 -> Csm,
    //    >=32 -> delta bf16.  [256x128 8-wave; K=1536; grid 416, %8==0]
    gemm_w8<3,0><<<dim3(416), dim3(512), 0, stream>>>(
        ub, 1536, Wt_x, 1536, deltab, 1536, Bsm, Csm, 1568, 1536, b_dt, 13);

    // 4-6) chunked selective scan (NCHUNK=128: 1536 blocks for A/C)
    scan_chunk_state<<<(BATCH*NCHUNK*D_INNER)/256, blk, 0, stream>>>(
        deltab, ub, Bsm, A_log, chunkS, dtsum);
    scan_chunk_scan<<<(BATCH*D_INNER*16 + 255)/256, blk, 0, stream>>>(
        A_log, dtsum, chunkS);
    scan_output<<<(BATCH*NCHUNK*D_INNER)/256, blk, 0, stream>>>(
        deltab, ub, Bsm, Csm, A_log, chunkS, xzb, yb);

    // 7) out = y @ W_out  (f32 out)  [128^2; grid 6*64=384, %8==0]
    gemm_p2<0,0><<<dim3(384), blk, 0, stream>>>(
        yb, 1536, Wt_out, 1536, out, 768, 768, 1536, 6);
}